// Round 1
// baseline (776.113 us; speedup 1.0000x reference)
//
#include <hip/hip_runtime.h>

#define NN 2048
#define TT 64
#define FF 16
#define HH 64
#define GG 192   // 3H
#define LL 16
#define TOPKK 10

// ---------------------------------------------------------------------------
// Kernel 1: GRU. 512 blocks x 128 threads, 4 samples per block.
// W_hh staged in LDS (XOR-swizzled chunks for bank spread). fp32 throughout.
// Writes h for t in [48,64) to h_tail (N,16,64).
// ---------------------------------------------------------------------------
__global__ __launch_bounds__(128) void gru_kernel(
    const float* __restrict__ x,      // (N,T,F)
    const float* __restrict__ W_ih,   // (192,16)
    const float* __restrict__ W_hh,   // (192,64)
    const float* __restrict__ b_ih,   // (192,)
    const float* __restrict__ b_hh,   // (192,)
    float* __restrict__ h_tail)       // (N,16,64)
{
    __shared__ __attribute__((aligned(16))) float Whh_s[GG * HH];   // swizzled, 48KB
    __shared__ __attribute__((aligned(16))) float h_s[4 * HH];      // swizzled
    __shared__ __attribute__((aligned(16))) float Arz[4 * 132];
    __shared__ __attribute__((aligned(16))) float Axn[4 * 68];
    __shared__ __attribute__((aligned(16))) float Ahn[4 * 68];
    __shared__ __attribute__((aligned(16))) float x_s[2][4 * 20];

    const int t  = threadIdx.x;
    const int n0 = blockIdx.x * 4;

    // stage W_hh swizzled: chunk ci of row j at j*64 + ((ci^(j&15))<<2)
    for (int c = t; c < GG * HH / 4; c += 128) {
        const int j = c >> 4, ci = c & 15;
        const float4 v = *(const float4*)(W_hh + c * 4);
        *(float4*)(Whh_s + j * 64 + ((ci ^ (j & 15)) << 2)) = v;
    }
    // zero h
    h_s[t] = 0.f; h_s[t + 128] = 0.f;

    const int sg = t & 1;    // sample group: samples 2sg, 2sg+1
    const int jg = t >> 1;   // 0..63 -> rows 3jg..3jg+2
    float wih[3][16];
    float bi_r[3], bh_r[3];
#pragma unroll
    for (int cj = 0; cj < 3; ++cj) {
        const int j = 3 * jg + cj;
        bi_r[cj] = b_ih[j];
        bh_r[cj] = b_hh[j];
#pragma unroll
        for (int i = 0; i < 16; ++i) wih[cj][i] = W_ih[j * 16 + i];
    }
    // stage x step 0
    if (t < 16) {
        const int s = t >> 2, ci = t & 3;
        *(float4*)(x_s[0] + s * 20 + ci * 4) =
            *(const float4*)(x + ((size_t)(n0 + s) * TT + 0) * FF + ci * 4);
    }
    __syncthreads();

    for (int step = 0; step < TT; ++step) {
        const int p = step & 1;
        float xacc[2][3], hacc[2][3];
#pragma unroll
        for (int cs = 0; cs < 2; ++cs)
#pragma unroll
            for (int cj = 0; cj < 3; ++cj) { xacc[cs][cj] = bi_r[cj]; hacc[cs][cj] = bh_r[cj]; }

        // xp = x_t @ W_ih^T
#pragma unroll
        for (int ci = 0; ci < 4; ++ci) {
            float4 xv[2];
            xv[0] = *(const float4*)(x_s[p] + (2 * sg + 0) * 20 + ci * 4);
            xv[1] = *(const float4*)(x_s[p] + (2 * sg + 1) * 20 + ci * 4);
#pragma unroll
            for (int cs = 0; cs < 2; ++cs) {
#pragma unroll
                for (int cj = 0; cj < 3; ++cj) {
                    xacc[cs][cj] += xv[cs].x * wih[cj][4 * ci + 0] + xv[cs].y * wih[cj][4 * ci + 1]
                                  + xv[cs].z * wih[cj][4 * ci + 2] + xv[cs].w * wih[cj][4 * ci + 3];
                }
            }
        }
        // gh = h @ W_hh^T
#pragma unroll
        for (int ci = 0; ci < 16; ++ci) {
            float4 hv[2], wv[3];
            hv[0] = *(const float4*)(h_s + (2 * sg + 0) * 64 + ((ci ^ (2 * sg + 0)) << 2));
            hv[1] = *(const float4*)(h_s + (2 * sg + 1) * 64 + ((ci ^ (2 * sg + 1)) << 2));
#pragma unroll
            for (int cj = 0; cj < 3; ++cj) {
                const int j = 3 * jg + cj;
                wv[cj] = *(const float4*)(Whh_s + j * 64 + ((ci ^ (j & 15)) << 2));
            }
#pragma unroll
            for (int cs = 0; cs < 2; ++cs)
#pragma unroll
                for (int cj = 0; cj < 3; ++cj)
                    hacc[cs][cj] += hv[cs].x * wv[cj].x + hv[cs].y * wv[cj].y
                                  + hv[cs].z * wv[cj].z + hv[cs].w * wv[cj].w;
        }
        // write preactivations
#pragma unroll
        for (int cs = 0; cs < 2; ++cs) {
            const int s = 2 * sg + cs;
#pragma unroll
            for (int cj = 0; cj < 3; ++cj) {
                const int j = 3 * jg + cj;
                if (j < 128) Arz[s * 132 + j] = xacc[cs][cj] + hacc[cs][cj];
                else { Axn[s * 68 + j - 128] = xacc[cs][cj]; Ahn[s * 68 + j - 128] = hacc[cs][cj]; }
            }
        }
        __syncthreads();

        // stage next x during pointwise phase
        if (t < 16 && step + 1 < TT) {
            const int s = t >> 2, ci = t & 3;
            *(float4*)(x_s[p ^ 1] + s * 20 + ci * 4) =
                *(const float4*)(x + ((size_t)(n0 + s) * TT + (step + 1)) * FF + ci * 4);
        }
        // pointwise gates: 256 units / 128 threads
#pragma unroll
        for (int k = 0; k < 2; ++k) {
            const int u = t + k * 128;
            const int s = u >> 6, jj = u & 63;
            const float r  = 1.f / (1.f + expf(-Arz[s * 132 + jj]));
            const float z  = 1.f / (1.f + expf(-Arz[s * 132 + 64 + jj]));
            const float xn = Axn[s * 68 + jj];
            const float hn = Ahn[s * 68 + jj];
            const float nn = tanhf(xn + r * hn);
            const int ph = s * 64 + (((jj >> 2) ^ s) << 2) + (jj & 3);
            const float hold = h_s[ph];
            const float hnew = (1.f - z) * nn + z * hold;
            h_s[ph] = hnew;
            if (step >= 48)
                h_tail[((size_t)(n0 + s) * LL + (step - 48)) * HH + jj] = hnew;
        }
        __syncthreads();
    }
}

// ---------------------------------------------------------------------------
// Kernel 2: K = h_tail @ Wk^T.  2048 blocks (one per sample) x 256 threads.
// ---------------------------------------------------------------------------
__global__ __launch_bounds__(256) void kproj_kernel(
    const float* __restrict__ h_tail, // (N,16,64)
    const float* __restrict__ Wk,     // (64,64)
    float* __restrict__ Kout)         // (N,16,64) == (N*16, 64) rows
{
    __shared__ __attribute__((aligned(16))) float Wk_s[64 * 68];
    __shared__ __attribute__((aligned(16))) float hs2[16 * 68];
    const int t = threadIdx.x;
    const int n = blockIdx.x;

    for (int c = t; c < 1024; c += 256) {          // 64x64 floats = 1024 float4
        const int j = c >> 4, ci = c & 15;
        *(float4*)(Wk_s + j * 68 + ci * 4) = *(const float4*)(Wk + c * 4);
    }
    {
        const int l = t >> 4, ci = t & 15;
        *(float4*)(hs2 + l * 68 + ci * 4) = *(const float4*)(h_tail + (size_t)n * 1024 + t * 4);
    }
    __syncthreads();

    const int l = t >> 4, qd = t & 15;
    float acc[4] = {0.f, 0.f, 0.f, 0.f};
#pragma unroll
    for (int ci = 0; ci < 16; ++ci) {
        const float4 hv = *(const float4*)(hs2 + l * 68 + ci * 4);
#pragma unroll
        for (int c = 0; c < 4; ++c) {
            const int j = qd + 16 * c;
            const float4 wv = *(const float4*)(Wk_s + j * 68 + ci * 4);
            acc[c] += hv.x * wv.x + hv.y * wv.y + hv.z * wv.z + hv.w * wv.w;
        }
    }
    float* ko = Kout + ((size_t)n * LL + l) * HH;
#pragma unroll
    for (int c = 0; c < 4; ++c) ko[qd + 16 * c] = acc[c];
}

// ---------------------------------------------------------------------------
// Kernel 3: fused Q-proj + scores + top-10 + softmax-gather + MLP.
// 256 blocks (8 queries each) x 512 threads. Each block streams all K rows.
// ---------------------------------------------------------------------------
__global__ __launch_bounds__(512) void score_kernel(
    const float* __restrict__ x,      // (N,T,F)
    const float* __restrict__ h_tail, // (N,16,64)
    const float* __restrict__ Wq,     // (64,64)
    const float* __restrict__ Kmat,   // (N*16,64)
    const float* __restrict__ W1, const float* __restrict__ b1,
    const float* __restrict__ W2, const float* __restrict__ b2,
    float* __restrict__ out)          // (N,)
{
    __shared__ __attribute__((aligned(16))) float Qs[8 * 68];
    __shared__ float cand_v[512];
    __shared__ int   cand_i[512];
    __shared__ float topv[8][TOPKK];
    __shared__ int   topi[8][TOPKK];

    const int t  = threadIdx.x;
    const int bb = blockIdx.x;

    // Q projection: 8 queries x 64 dims = 512 outputs, one per thread
    {
        const int qq = t >> 6, jj = t & 63;
        const float* hrow = h_tail + ((size_t)(bb * 8 + qq) * LL + 15) * HH;
        const float* wrow = Wq + jj * HH;
        float a = 0.f;
#pragma unroll 16
        for (int i = 0; i < 64; ++i) a += hrow[i] * wrow[i];
        Qs[qq * 68 + jj] = a;
    }
    __syncthreads();

    const int q   = t & 7;        // query within block
    const int rg  = t >> 3;       // 0..63 row group
    const int myn = bb * 8 + q;

    float4 qv[16];
#pragma unroll
    for (int ci = 0; ci < 16; ++ci) qv[ci] = *(const float4*)(Qs + q * 68 + ci * 4);

    float v[TOPKK]; int id[TOPKK];
#pragma unroll
    for (int r = 0; r < TOPKK; ++r) { v[r] = -3e38f; id[r] = -1; }
    float vmin = -3e38f; int imin = 0;

    // stream all 32768 K rows; this thread: rows it*64 + rg, 512 of them (x2 unroll)
    for (int it = 0; it < 512; it += 2) {
        const float* kr0 = Kmat + ((size_t)it * 64 + rg) * 64;
        const float* kr1 = kr0 + 64 * 64;
        float s0a = 0.f, s0b = 0.f, s0c = 0.f, s0d = 0.f;
        float s1a = 0.f, s1b = 0.f, s1c = 0.f, s1d = 0.f;
#pragma unroll
        for (int ci = 0; ci < 16; ci += 4) {
            const float4 k0a = *(const float4*)(kr0 + ci * 4);
            const float4 k0b = *(const float4*)(kr0 + ci * 4 + 4);
            const float4 k0c = *(const float4*)(kr0 + ci * 4 + 8);
            const float4 k0d = *(const float4*)(kr0 + ci * 4 + 12);
            const float4 k1a = *(const float4*)(kr1 + ci * 4);
            const float4 k1b = *(const float4*)(kr1 + ci * 4 + 4);
            const float4 k1c = *(const float4*)(kr1 + ci * 4 + 8);
            const float4 k1d = *(const float4*)(kr1 + ci * 4 + 12);
            s0a += qv[ci].x * k0a.x + qv[ci].y * k0a.y + qv[ci].z * k0a.z + qv[ci].w * k0a.w;
            s0b += qv[ci + 1].x * k0b.x + qv[ci + 1].y * k0b.y + qv[ci + 1].z * k0b.z + qv[ci + 1].w * k0b.w;
            s0c += qv[ci + 2].x * k0c.x + qv[ci + 2].y * k0c.y + qv[ci + 2].z * k0c.z + qv[ci + 2].w * k0c.w;
            s0d += qv[ci + 3].x * k0d.x + qv[ci + 3].y * k0d.y + qv[ci + 3].z * k0d.z + qv[ci + 3].w * k0d.w;
            s1a += qv[ci].x * k1a.x + qv[ci].y * k1a.y + qv[ci].z * k1a.z + qv[ci].w * k1a.w;
            s1b += qv[ci + 1].x * k1b.x + qv[ci + 1].y * k1b.y + qv[ci + 1].z * k1b.z + qv[ci + 1].w * k1b.w;
            s1c += qv[ci + 2].x * k1c.x + qv[ci + 2].y * k1c.y + qv[ci + 2].z * k1c.z + qv[ci + 2].w * k1c.w;
            s1d += qv[ci + 3].x * k1d.x + qv[ci + 3].y * k1d.y + qv[ci + 3].z * k1d.z + qv[ci + 3].w * k1d.w;
        }
        const float s0 = (s0a + s0b) + (s0c + s0d);
        const float s1 = (s1a + s1b) + (s1c + s1d);
        const int row0 = it * 64 + rg;
        const int row1 = row0 + 64;
        if ((row0 >> 4) != myn && s0 > vmin) {
            v[imin] = s0; id[imin] = row0;
            vmin = v[0]; imin = 0;
#pragma unroll
            for (int r = 1; r < TOPKK; ++r) if (v[r] < vmin) { vmin = v[r]; imin = r; }
        }
        if ((row1 >> 4) != myn && s1 > vmin) {
            v[imin] = s1; id[imin] = row1;
            vmin = v[0]; imin = 0;
#pragma unroll
            for (int r = 1; r < TOPKK; ++r) if (v[r] < vmin) { vmin = v[r]; imin = r; }
        }
    }

    // 10-round block-wide selection (64 slots per query)
    unsigned used = 0;
    for (int r = 0; r < TOPKK; ++r) {
        float bv = -3e38f; int bi = -1, bslot = -1;
#pragma unroll
        for (int s2 = 0; s2 < TOPKK; ++s2)
            if (!((used >> s2) & 1) && v[s2] > bv) { bv = v[s2]; bi = id[s2]; bslot = s2; }
        cand_v[t] = bv; cand_i[t] = bi;
        __syncthreads();
        for (int st = 32; st >= 1; st >>= 1) {
            if (rg < st) {
                const int o = t + 8 * st;
                if (cand_v[o] > cand_v[t]) { cand_v[t] = cand_v[o]; cand_i[t] = cand_i[o]; }
            }
            __syncthreads();
        }
        const int wi = cand_i[q];
        if (bslot >= 0 && bi == wi) used |= (1u << bslot);
        if (rg == 0) { topv[q][r] = cand_v[q]; topi[q][r] = wi; }
        __syncthreads();
    }

    // finalize: softmax over top-10, gather leader feats, MLP -> out
    if (t < 8) {
        const float mx = topv[t][0];   // rounds emit descending order
        float w[TOPKK]; float sum = 0.f;
#pragma unroll
        for (int r = 0; r < TOPKK; ++r) { w[r] = __expf(topv[t][r] - mx); sum += w[r]; }
        const float inv = 1.f / sum;
        float feat[FF];
#pragma unroll
        for (int f = 0; f < FF; ++f) feat[f] = 0.f;
        for (int r = 0; r < TOPKK; ++r) {
            const int wi = topi[t][r];
            const int m = wi >> 4, l = wi & 15;
            const float* xr = x + ((size_t)m * TT + (48 + l)) * FF;
            const float wr = w[r] * inv;
#pragma unroll
            for (int f = 0; f < FF; ++f) feat[f] += wr * xr[f];
        }
        float o = 0.f;
#pragma unroll
        for (int oo = 0; oo < FF; ++oo) {
            float hh = b1[oo];
#pragma unroll
            for (int f = 0; f < FF; ++f) hh += feat[f] * W1[oo * FF + f];
            hh = hh > 0.f ? hh : 0.01f * hh;
            o += hh * W2[oo];
        }
        o += b2[0];
        out[bb * 8 + t] = o;
    }
}

// ---------------------------------------------------------------------------
extern "C" void kernel_launch(void* const* d_in, const int* in_sizes, int n_in,
                              void* d_out, int out_size, void* d_ws, size_t ws_size,
                              hipStream_t stream) {
    const float* x    = (const float*)d_in[0];
    const float* W_ih = (const float*)d_in[1];
    const float* W_hh = (const float*)d_in[2];
    const float* b_ih = (const float*)d_in[3];
    const float* b_hh = (const float*)d_in[4];
    const float* Wq   = (const float*)d_in[5];
    const float* Wk   = (const float*)d_in[6];
    const float* W1   = (const float*)d_in[7];
    const float* b1   = (const float*)d_in[8];
    const float* W2   = (const float*)d_in[9];
    const float* b2   = (const float*)d_in[10];
    float* outp = (float*)d_out;

    float* h_tail = (float*)d_ws;                          // 2048*16*64 f32 = 8MB
    float* Kmat   = h_tail + (size_t)NN * LL * HH;         // 8MB
    (void)ws_size; (void)n_in; (void)in_sizes; (void)out_size;

    gru_kernel<<<NN / 4, 128, 0, stream>>>(x, W_ih, W_hh, b_ih, b_hh, h_tail);
    kproj_kernel<<<NN, 256, 0, stream>>>(h_tail, Wk, Kmat);
    score_kernel<<<NN / 8, 512, 0, stream>>>(x, h_tail, Wq, Kmat, W1, b1, W2, b2, outp);
}

// Round 2
// 745.669 us; speedup vs baseline: 1.0408x; 1.0408x over previous
//
#include <hip/hip_runtime.h>

#define NN 2048
#define TT 64
#define FF 16
#define HH 64
#define GG 192   // 3H
#define LL 16
#define TOPKK 10

#define KSTRIDE 68            // padded K row stride in floats (272 B): bank-conflict-free
#define TILE_ROWS 256
#define NTILES 128            // 32768 / 256
#define TILE_BYTES (TILE_ROWS * KSTRIDE * 4)   // 69632

// async global->LDS, 16B per lane
__device__ __forceinline__ void async_copy16(const void* g, void* l) {
    __builtin_amdgcn_global_load_lds(
        (const __attribute__((address_space(1))) unsigned int*)g,
        (__attribute__((address_space(3))) unsigned int*)l,
        16, 0, 0);
}

// ---------------------------------------------------------------------------
// Kernel 1: GRU (unchanged from R1). 512 blocks x 128 threads, 4 samples/block.
// ---------------------------------------------------------------------------
__global__ __launch_bounds__(128) void gru_kernel(
    const float* __restrict__ x,      // (N,T,F)
    const float* __restrict__ W_ih,   // (192,16)
    const float* __restrict__ W_hh,   // (192,64)
    const float* __restrict__ b_ih,   // (192,)
    const float* __restrict__ b_hh,   // (192,)
    float* __restrict__ h_tail)       // (N,16,64)
{
    __shared__ __attribute__((aligned(16))) float Whh_s[GG * HH];
    __shared__ __attribute__((aligned(16))) float h_s[4 * HH];
    __shared__ __attribute__((aligned(16))) float Arz[4 * 132];
    __shared__ __attribute__((aligned(16))) float Axn[4 * 68];
    __shared__ __attribute__((aligned(16))) float Ahn[4 * 68];
    __shared__ __attribute__((aligned(16))) float x_s[2][4 * 20];

    const int t  = threadIdx.x;
    const int n0 = blockIdx.x * 4;

    for (int c = t; c < GG * HH / 4; c += 128) {
        const int j = c >> 4, ci = c & 15;
        const float4 v = *(const float4*)(W_hh + c * 4);
        *(float4*)(Whh_s + j * 64 + ((ci ^ (j & 15)) << 2)) = v;
    }
    h_s[t] = 0.f; h_s[t + 128] = 0.f;

    const int sg = t & 1;
    const int jg = t >> 1;
    float wih[3][16];
    float bi_r[3], bh_r[3];
#pragma unroll
    for (int cj = 0; cj < 3; ++cj) {
        const int j = 3 * jg + cj;
        bi_r[cj] = b_ih[j];
        bh_r[cj] = b_hh[j];
#pragma unroll
        for (int i = 0; i < 16; ++i) wih[cj][i] = W_ih[j * 16 + i];
    }
    if (t < 16) {
        const int s = t >> 2, ci = t & 3;
        *(float4*)(x_s[0] + s * 20 + ci * 4) =
            *(const float4*)(x + ((size_t)(n0 + s) * TT + 0) * FF + ci * 4);
    }
    __syncthreads();

    for (int step = 0; step < TT; ++step) {
        const int p = step & 1;
        float xacc[2][3], hacc[2][3];
#pragma unroll
        for (int cs = 0; cs < 2; ++cs)
#pragma unroll
            for (int cj = 0; cj < 3; ++cj) { xacc[cs][cj] = bi_r[cj]; hacc[cs][cj] = bh_r[cj]; }

#pragma unroll
        for (int ci = 0; ci < 4; ++ci) {
            float4 xv[2];
            xv[0] = *(const float4*)(x_s[p] + (2 * sg + 0) * 20 + ci * 4);
            xv[1] = *(const float4*)(x_s[p] + (2 * sg + 1) * 20 + ci * 4);
#pragma unroll
            for (int cs = 0; cs < 2; ++cs) {
#pragma unroll
                for (int cj = 0; cj < 3; ++cj) {
                    xacc[cs][cj] += xv[cs].x * wih[cj][4 * ci + 0] + xv[cs].y * wih[cj][4 * ci + 1]
                                  + xv[cs].z * wih[cj][4 * ci + 2] + xv[cs].w * wih[cj][4 * ci + 3];
                }
            }
        }
#pragma unroll
        for (int ci = 0; ci < 16; ++ci) {
            float4 hv[2], wv[3];
            hv[0] = *(const float4*)(h_s + (2 * sg + 0) * 64 + ((ci ^ (2 * sg + 0)) << 2));
            hv[1] = *(const float4*)(h_s + (2 * sg + 1) * 64 + ((ci ^ (2 * sg + 1)) << 2));
#pragma unroll
            for (int cj = 0; cj < 3; ++cj) {
                const int j = 3 * jg + cj;
                wv[cj] = *(const float4*)(Whh_s + j * 64 + ((ci ^ (j & 15)) << 2));
            }
#pragma unroll
            for (int cs = 0; cs < 2; ++cs)
#pragma unroll
                for (int cj = 0; cj < 3; ++cj)
                    hacc[cs][cj] += hv[cs].x * wv[cj].x + hv[cs].y * wv[cj].y
                                  + hv[cs].z * wv[cj].z + hv[cs].w * wv[cj].w;
        }
#pragma unroll
        for (int cs = 0; cs < 2; ++cs) {
            const int s = 2 * sg + cs;
#pragma unroll
            for (int cj = 0; cj < 3; ++cj) {
                const int j = 3 * jg + cj;
                if (j < 128) Arz[s * 132 + j] = xacc[cs][cj] + hacc[cs][cj];
                else { Axn[s * 68 + j - 128] = xacc[cs][cj]; Ahn[s * 68 + j - 128] = hacc[cs][cj]; }
            }
        }
        __syncthreads();

        if (t < 16 && step + 1 < TT) {
            const int s = t >> 2, ci = t & 3;
            *(float4*)(x_s[p ^ 1] + s * 20 + ci * 4) =
                *(const float4*)(x + ((size_t)(n0 + s) * TT + (step + 1)) * FF + ci * 4);
        }
#pragma unroll
        for (int k = 0; k < 2; ++k) {
            const int u = t + k * 128;
            const int s = u >> 6, jj = u & 63;
            const float r  = 1.f / (1.f + expf(-Arz[s * 132 + jj]));
            const float z  = 1.f / (1.f + expf(-Arz[s * 132 + 64 + jj]));
            const float xn = Axn[s * 68 + jj];
            const float hn = Ahn[s * 68 + jj];
            const float nn = tanhf(xn + r * hn);
            const int ph = s * 64 + (((jj >> 2) ^ s) << 2) + (jj & 3);
            const float hold = h_s[ph];
            const float hnew = (1.f - z) * nn + z * hold;
            h_s[ph] = hnew;
            if (step >= 48)
                h_tail[((size_t)(n0 + s) * LL + (step - 48)) * HH + jj] = hnew;
        }
        __syncthreads();
    }
}

// ---------------------------------------------------------------------------
// Kernel 2: K = h_tail @ Wk^T, written with PADDED row stride (68 floats).
// ---------------------------------------------------------------------------
__global__ __launch_bounds__(256) void kproj_kernel(
    const float* __restrict__ h_tail, // (N,16,64)
    const float* __restrict__ Wk,     // (64,64)
    float* __restrict__ Kout)         // (N*16, 68) padded rows
{
    __shared__ __attribute__((aligned(16))) float Wk_s[64 * 68];
    __shared__ __attribute__((aligned(16))) float hs2[16 * 68];
    const int t = threadIdx.x;
    const int n = blockIdx.x;

    for (int c = t; c < 1024; c += 256) {
        const int j = c >> 4, ci = c & 15;
        *(float4*)(Wk_s + j * 68 + ci * 4) = *(const float4*)(Wk + c * 4);
    }
    {
        const int l = t >> 4, ci = t & 15;
        *(float4*)(hs2 + l * 68 + ci * 4) = *(const float4*)(h_tail + (size_t)n * 1024 + t * 4);
    }
    __syncthreads();

    const int l = t >> 4, qd = t & 15;
    float acc[4] = {0.f, 0.f, 0.f, 0.f};
#pragma unroll
    for (int ci = 0; ci < 16; ++ci) {
        const float4 hv = *(const float4*)(hs2 + l * 68 + ci * 4);
#pragma unroll
        for (int c = 0; c < 4; ++c) {
            const int j = qd + 16 * c;
            const float4 wv = *(const float4*)(Wk_s + j * 68 + ci * 4);
            acc[c] += hv.x * wv.x + hv.y * wv.y + hv.z * wv.z + hv.w * wv.w;
        }
    }
    float* ko = Kout + (size_t)(n * LL + l) * KSTRIDE;
#pragma unroll
    for (int c = 0; c < 4; ++c) ko[qd + 16 * c] = acc[c];
}

// ---------------------------------------------------------------------------
// Kernel 3: fused Q-proj + scores + top-10 + softmax-gather + MLP.
// 256 blocks x 512 threads, 8 queries/block. K streamed through
// double-buffered LDS via global_load_lds; each thread scores 2 queries
// (LDS broadcast across the 4 query-pair lanes, 2-way bank alias = free).
// ---------------------------------------------------------------------------
__global__ __launch_bounds__(512, 2) void score_kernel(
    const float* __restrict__ x,      // (N,T,F)
    const float* __restrict__ h_tail, // (N,16,64)
    const float* __restrict__ Wq,     // (64,64)
    const float* __restrict__ Kmat,   // (32768, 68) padded
    const float* __restrict__ W1, const float* __restrict__ b1,
    const float* __restrict__ W2, const float* __restrict__ b2,
    float* __restrict__ out)          // (N,)
{
    __shared__ __attribute__((aligned(16))) float Kbuf[2][TILE_ROWS * KSTRIDE]; // 2x68KB
    __shared__ __attribute__((aligned(16))) float Qs[8 * 68];
    __shared__ float cand_v[8 * 128];
    __shared__ int   cand_i[8 * 128];
    __shared__ float topv[8][TOPKK];
    __shared__ int   topi[8][TOPKK];

    const int t  = threadIdx.x;
    const int bb = blockIdx.x;

    // kick off staging of tile 0 ASAP
    {
        const char* src = (const char*)Kmat;
        char* dst = (char*)&Kbuf[0][0];
#pragma unroll
        for (int r = 0; r < 8; ++r)
            async_copy16(src + r * 8192 + t * 16, dst + r * 8192 + t * 16);
        if (t < 256) async_copy16(src + 65536 + t * 16, dst + 65536 + t * 16);
    }

    // Q projection: 8 queries x 64 dims, one output per thread
    {
        const int qq = t >> 6, jj = t & 63;
        const float* hrow = h_tail + ((size_t)(bb * 8 + qq) * LL + 15) * HH;
        const float* wrow = Wq + jj * HH;
        float a = 0.f;
#pragma unroll 16
        for (int i = 0; i < 64; ++i) a += hrow[i] * wrow[i];
        Qs[qq * 68 + jj] = a;
    }

    const int qp = t & 3;         // query pair 0..3
    const int rg = t >> 2;        // row group 0..127
    const int q0 = qp * 2;
    const int myn0 = bb * 8 + q0, myn1 = myn0 + 1;

    float v0[TOPKK], v1[TOPKK]; int id0[TOPKK], id1[TOPKK];
#pragma unroll
    for (int r = 0; r < TOPKK; ++r) { v0[r] = -3e38f; v1[r] = -3e38f; id0[r] = -1; id1[r] = -1; }
    float vmin0 = -3e38f, vmin1 = -3e38f; int imin0 = 0, imin1 = 0;

    __syncthreads();   // Qs ready (also drains tile-0 staging)

    float4 qv0[16], qv1[16];
#pragma unroll
    for (int ci = 0; ci < 16; ++ci) {
        qv0[ci] = *(const float4*)(Qs + q0 * 68 + ci * 4);
        qv1[ci] = *(const float4*)(Qs + (q0 + 1) * 68 + ci * 4);
    }

    for (int tile = 0; tile < NTILES; ++tile) {
        asm volatile("s_waitcnt vmcnt(0)" ::: "memory");
        __syncthreads();
        if (tile + 1 < NTILES) {
            const char* src = (const char*)Kmat + (size_t)(tile + 1) * TILE_BYTES;
            char* dst = (char*)&Kbuf[(tile + 1) & 1][0];
#pragma unroll
            for (int r = 0; r < 8; ++r)
                async_copy16(src + r * 8192 + t * 16, dst + r * 8192 + t * 16);
            if (t < 256) async_copy16(src + 65536 + t * 16, dst + 65536 + t * 16);
        }
        const float* kb = &Kbuf[tile & 1][0];
#pragma unroll
        for (int rr = 0; rr < 2; ++rr) {
            const int lr = rg + rr * 128;
            const float4* kr = (const float4*)(kb + lr * KSTRIDE);
            float a0 = 0.f, a1 = 0.f, a2 = 0.f, a3 = 0.f;
            float c0 = 0.f, c1 = 0.f, c2 = 0.f, c3 = 0.f;
#pragma unroll
            for (int ci = 0; ci < 16; ci += 4) {
                const float4 k0 = kr[ci], k1 = kr[ci + 1], k2 = kr[ci + 2], k3 = kr[ci + 3];
                a0 += qv0[ci].x * k0.x + qv0[ci].y * k0.y + qv0[ci].z * k0.z + qv0[ci].w * k0.w;
                a1 += qv0[ci + 1].x * k1.x + qv0[ci + 1].y * k1.y + qv0[ci + 1].z * k1.z + qv0[ci + 1].w * k1.w;
                a2 += qv0[ci + 2].x * k2.x + qv0[ci + 2].y * k2.y + qv0[ci + 2].z * k2.z + qv0[ci + 2].w * k2.w;
                a3 += qv0[ci + 3].x * k3.x + qv0[ci + 3].y * k3.y + qv0[ci + 3].z * k3.z + qv0[ci + 3].w * k3.w;
                c0 += qv1[ci].x * k0.x + qv1[ci].y * k0.y + qv1[ci].z * k0.z + qv1[ci].w * k0.w;
                c1 += qv1[ci + 1].x * k1.x + qv1[ci + 1].y * k1.y + qv1[ci + 1].z * k1.z + qv1[ci + 1].w * k1.w;
                c2 += qv1[ci + 2].x * k2.x + qv1[ci + 2].y * k2.y + qv1[ci + 2].z * k2.z + qv1[ci + 2].w * k2.w;
                c3 += qv1[ci + 3].x * k3.x + qv1[ci + 3].y * k3.y + qv1[ci + 3].z * k3.z + qv1[ci + 3].w * k3.w;
            }
            const float s0 = (a0 + a1) + (a2 + a3);
            const float s1 = (c0 + c1) + (c2 + c3);
            const int grow = tile * TILE_ROWS + lr;
            const int m = grow >> 4;
            if (m != myn0 && s0 > vmin0) {
                v0[imin0] = s0; id0[imin0] = grow;
                vmin0 = v0[0]; imin0 = 0;
#pragma unroll
                for (int r = 1; r < TOPKK; ++r) if (v0[r] < vmin0) { vmin0 = v0[r]; imin0 = r; }
            }
            if (m != myn1 && s1 > vmin1) {
                v1[imin1] = s1; id1[imin1] = grow;
                vmin1 = v1[0]; imin1 = 0;
#pragma unroll
                for (int r = 1; r < TOPKK; ++r) if (v1[r] < vmin1) { vmin1 = v1[r]; imin1 = r; }
            }
        }
    }

    // ---- block-wide 10-round top-k merge (128 candidates per query) ----
    unsigned used0 = 0, used1 = 0;
    for (int r = 0; r < TOPKK; ++r) {
        float bv0 = -3e38f, bv1 = -3e38f; int bi0 = -1, bi1 = -1, bs0 = -1, bs1 = -1;
#pragma unroll
        for (int s = 0; s < TOPKK; ++s) {
            if (!((used0 >> s) & 1) && v0[s] > bv0) { bv0 = v0[s]; bi0 = id0[s]; bs0 = s; }
            if (!((used1 >> s) & 1) && v1[s] > bv1) { bv1 = v1[s]; bi1 = id1[s]; bs1 = s; }
        }
        cand_v[q0 * 128 + rg] = bv0;       cand_i[q0 * 128 + rg] = bi0;
        cand_v[(q0 + 1) * 128 + rg] = bv1; cand_i[(q0 + 1) * 128 + rg] = bi1;
        __syncthreads();
        for (int st = 64; st >= 1; st >>= 1) {
            if (rg < st) {
                const int i0 = q0 * 128 + rg, i1 = (q0 + 1) * 128 + rg;
                if (cand_v[i0 + st] > cand_v[i0]) { cand_v[i0] = cand_v[i0 + st]; cand_i[i0] = cand_i[i0 + st]; }
                if (cand_v[i1 + st] > cand_v[i1]) { cand_v[i1] = cand_v[i1 + st]; cand_i[i1] = cand_i[i1 + st]; }
            }
            __syncthreads();
        }
        const int w0 = cand_i[q0 * 128], w1 = cand_i[(q0 + 1) * 128];
        if (bs0 >= 0 && bi0 == w0) used0 |= (1u << bs0);
        if (bs1 >= 0 && bi1 == w1) used1 |= (1u << bs1);
        if (rg == 0) {
            topv[q0][r] = cand_v[q0 * 128];           topi[q0][r] = w0;
            topv[q0 + 1][r] = cand_v[(q0 + 1) * 128]; topi[q0 + 1][r] = w1;
        }
        __syncthreads();
    }

    // ---- softmax over top-10, gather leader feats, MLP ----
    if (t < 8) {
        const float mx = topv[t][0];
        float w[TOPKK]; float sum = 0.f;
#pragma unroll
        for (int r = 0; r < TOPKK; ++r) { w[r] = __expf(topv[t][r] - mx); sum += w[r]; }
        const float inv = 1.f / sum;
        float feat[FF];
#pragma unroll
        for (int f = 0; f < FF; ++f) feat[f] = 0.f;
        for (int r = 0; r < TOPKK; ++r) {
            const int wi = topi[t][r];
            const int m = wi >> 4, l = wi & 15;
            const float* xr = x + ((size_t)m * TT + (48 + l)) * FF;
            const float wr = w[r] * inv;
#pragma unroll
            for (int f = 0; f < FF; ++f) feat[f] += wr * xr[f];
        }
        float o = 0.f;
#pragma unroll
        for (int oo = 0; oo < FF; ++oo) {
            float hh = b1[oo];
#pragma unroll
            for (int f = 0; f < FF; ++f) hh += feat[f] * W1[oo * FF + f];
            hh = hh > 0.f ? hh : 0.01f * hh;
            o += hh * W2[oo];
        }
        o += b2[0];
        out[bb * 8 + t] = o;
    }
}

// ---------------------------------------------------------------------------
extern "C" void kernel_launch(void* const* d_in, const int* in_sizes, int n_in,
                              void* d_out, int out_size, void* d_ws, size_t ws_size,
                              hipStream_t stream) {
    const float* x    = (const float*)d_in[0];
    const float* W_ih = (const float*)d_in[1];
    const float* W_hh = (const float*)d_in[2];
    const float* b_ih = (const float*)d_in[3];
    const float* b_hh = (const float*)d_in[4];
    const float* Wq   = (const float*)d_in[5];
    const float* Wk   = (const float*)d_in[6];
    const float* W1   = (const float*)d_in[7];
    const float* b1   = (const float*)d_in[8];
    const float* W2   = (const float*)d_in[9];
    const float* b2   = (const float*)d_in[10];
    float* outp = (float*)d_out;

    float* h_tail = (float*)d_ws;                          // 2048*16*64 f32 = 8MB
    float* Kmat   = h_tail + (size_t)NN * LL * HH;         // 32768*68 f32 = 8.9MB
    (void)ws_size; (void)n_in; (void)in_sizes; (void)out_size;

    gru_kernel<<<NN / 4, 128, 0, stream>>>(x, W_ih, W_hh, b_ih, b_hh, h_tail);
    kproj_kernel<<<NN, 256, 0, stream>>>(h_tail, Wk, Kmat);
    score_kernel<<<NN / 8, 512, 0, stream>>>(x, h_tail, Wq, Kmat, W1, b1, W2, b2, outp);
}

// Round 3
// 458.819 us; speedup vs baseline: 1.6915x; 1.6252x over previous
//
#include <hip/hip_runtime.h>

#define NN 2048
#define TT 64
#define FF 16
#define HH 64
#define GG 192   // 3H
#define LL 16
#define TOPKK 10

#define CAP 960               // candidate-list capacity per query (ids overlay h_tail: 2048*960*4 < 8MB)

typedef __bf16 bf16x8 __attribute__((ext_vector_type(8)));
typedef float floatx4 __attribute__((ext_vector_type(4)));

union FragCast { uint4 u; bf16x8 b; };

__device__ __forceinline__ unsigned short f2bf(float f) {
    unsigned u = __float_as_uint(f);
    unsigned r = (u + 0x7fff + ((u >> 16) & 1)) >> 16;
    return (unsigned short)r;
}

// ---------------------------------------------------------------------------
// Kernel 1: GRU (unchanged). 512 blocks x 128 threads, 4 samples/block.
// ---------------------------------------------------------------------------
__global__ __launch_bounds__(128) void gru_kernel(
    const float* __restrict__ x,      // (N,T,F)
    const float* __restrict__ W_ih,   // (192,16)
    const float* __restrict__ W_hh,   // (192,64)
    const float* __restrict__ b_ih,   // (192,)
    const float* __restrict__ b_hh,   // (192,)
    float* __restrict__ h_tail)       // (N,16,64)
{
    __shared__ __attribute__((aligned(16))) float Whh_s[GG * HH];
    __shared__ __attribute__((aligned(16))) float h_s[4 * HH];
    __shared__ __attribute__((aligned(16))) float Arz[4 * 132];
    __shared__ __attribute__((aligned(16))) float Axn[4 * 68];
    __shared__ __attribute__((aligned(16))) float Ahn[4 * 68];
    __shared__ __attribute__((aligned(16))) float x_s[2][4 * 20];

    const int t  = threadIdx.x;
    const int n0 = blockIdx.x * 4;

    for (int c = t; c < GG * HH / 4; c += 128) {
        const int j = c >> 4, ci = c & 15;
        const float4 v = *(const float4*)(W_hh + c * 4);
        *(float4*)(Whh_s + j * 64 + ((ci ^ (j & 15)) << 2)) = v;
    }
    h_s[t] = 0.f; h_s[t + 128] = 0.f;

    const int sg = t & 1;
    const int jg = t >> 1;
    float wih[3][16];
    float bi_r[3], bh_r[3];
#pragma unroll
    for (int cj = 0; cj < 3; ++cj) {
        const int j = 3 * jg + cj;
        bi_r[cj] = b_ih[j];
        bh_r[cj] = b_hh[j];
#pragma unroll
        for (int i = 0; i < 16; ++i) wih[cj][i] = W_ih[j * 16 + i];
    }
    if (t < 16) {
        const int s = t >> 2, ci = t & 3;
        *(float4*)(x_s[0] + s * 20 + ci * 4) =
            *(const float4*)(x + ((size_t)(n0 + s) * TT + 0) * FF + ci * 4);
    }
    __syncthreads();

    for (int step = 0; step < TT; ++step) {
        const int p = step & 1;
        float xacc[2][3], hacc[2][3];
#pragma unroll
        for (int cs = 0; cs < 2; ++cs)
#pragma unroll
            for (int cj = 0; cj < 3; ++cj) { xacc[cs][cj] = bi_r[cj]; hacc[cs][cj] = bh_r[cj]; }

#pragma unroll
        for (int ci = 0; ci < 4; ++ci) {
            float4 xv[2];
            xv[0] = *(const float4*)(x_s[p] + (2 * sg + 0) * 20 + ci * 4);
            xv[1] = *(const float4*)(x_s[p] + (2 * sg + 1) * 20 + ci * 4);
#pragma unroll
            for (int cs = 0; cs < 2; ++cs) {
#pragma unroll
                for (int cj = 0; cj < 3; ++cj) {
                    xacc[cs][cj] += xv[cs].x * wih[cj][4 * ci + 0] + xv[cs].y * wih[cj][4 * ci + 1]
                                  + xv[cs].z * wih[cj][4 * ci + 2] + xv[cs].w * wih[cj][4 * ci + 3];
                }
            }
        }
#pragma unroll
        for (int ci = 0; ci < 16; ++ci) {
            float4 hv[2], wv[3];
            hv[0] = *(const float4*)(h_s + (2 * sg + 0) * 64 + ((ci ^ (2 * sg + 0)) << 2));
            hv[1] = *(const float4*)(h_s + (2 * sg + 1) * 64 + ((ci ^ (2 * sg + 1)) << 2));
#pragma unroll
            for (int cj = 0; cj < 3; ++cj) {
                const int j = 3 * jg + cj;
                wv[cj] = *(const float4*)(Whh_s + j * 64 + ((ci ^ (j & 15)) << 2));
            }
#pragma unroll
            for (int cs = 0; cs < 2; ++cs)
#pragma unroll
                for (int cj = 0; cj < 3; ++cj)
                    hacc[cs][cj] += hv[cs].x * wv[cj].x + hv[cs].y * wv[cj].y
                                  + hv[cs].z * wv[cj].z + hv[cs].w * wv[cj].w;
        }
#pragma unroll
        for (int cs = 0; cs < 2; ++cs) {
            const int s = 2 * sg + cs;
#pragma unroll
            for (int cj = 0; cj < 3; ++cj) {
                const int j = 3 * jg + cj;
                if (j < 128) Arz[s * 132 + j] = xacc[cs][cj] + hacc[cs][cj];
                else { Axn[s * 68 + j - 128] = xacc[cs][cj]; Ahn[s * 68 + j - 128] = hacc[cs][cj]; }
            }
        }
        __syncthreads();

        if (t < 16 && step + 1 < TT) {
            const int s = t >> 2, ci = t & 3;
            *(float4*)(x_s[p ^ 1] + s * 20 + ci * 4) =
                *(const float4*)(x + ((size_t)(n0 + s) * TT + (step + 1)) * FF + ci * 4);
        }
#pragma unroll
        for (int k = 0; k < 2; ++k) {
            const int u = t + k * 128;
            const int s = u >> 6, jj = u & 63;
            const float r  = 1.f / (1.f + expf(-Arz[s * 132 + jj]));
            const float z  = 1.f / (1.f + expf(-Arz[s * 132 + 64 + jj]));
            const float xn = Axn[s * 68 + jj];
            const float hn = Ahn[s * 68 + jj];
            const float nn = tanhf(xn + r * hn);
            const int ph = s * 64 + (((jj >> 2) ^ s) << 2) + (jj & 3);
            const float hold = h_s[ph];
            const float hnew = (1.f - z) * nn + z * hold;
            h_s[ph] = hnew;
            if (step >= 48)
                h_tail[((size_t)(n0 + s) * LL + (step - 48)) * HH + jj] = hnew;
        }
        __syncthreads();
    }
}

// ---------------------------------------------------------------------------
// Kernel 2: prep. Per sample: K rows (fp32 + bf16) and Q row (fp32 + bf16).
// 2048 blocks x 256 threads.
// ---------------------------------------------------------------------------
__global__ __launch_bounds__(256) void prep_kernel(
    const float* __restrict__ h_tail, // (N,16,64)
    const float* __restrict__ Wk,     // (64,64)
    const float* __restrict__ Wq,     // (64,64)
    float* __restrict__ Kmat,         // (32768,64) fp32
    unsigned short* __restrict__ Kh,  // (32768,64) bf16
    float* __restrict__ Qf,           // (2048,64) fp32
    unsigned short* __restrict__ Qh)  // (2048,64) bf16
{
    __shared__ __attribute__((aligned(16))) float Wk_s[64 * 68];
    __shared__ __attribute__((aligned(16))) float Wq_s[64 * 68];
    __shared__ __attribute__((aligned(16))) float hs2[16 * 68];
    const int t = threadIdx.x;
    const int n = blockIdx.x;

    for (int c = t; c < 1024; c += 256) {
        const int j = c >> 4, ci = c & 15;
        *(float4*)(Wk_s + j * 68 + ci * 4) = *(const float4*)(Wk + c * 4);
        *(float4*)(Wq_s + j * 68 + ci * 4) = *(const float4*)(Wq + c * 4);
    }
    {
        const int l = t >> 4, ci = t & 15;
        *(float4*)(hs2 + l * 68 + ci * 4) = *(const float4*)(h_tail + (size_t)n * 1024 + t * 4);
    }
    __syncthreads();

    const int l = t >> 4, qd = t & 15;
    float acc[4] = {0.f, 0.f, 0.f, 0.f};
#pragma unroll
    for (int ci = 0; ci < 16; ++ci) {
        const float4 hv = *(const float4*)(hs2 + l * 68 + ci * 4);
#pragma unroll
        for (int c = 0; c < 4; ++c) {
            const int j = qd + 16 * c;
            const float4 wv = *(const float4*)(Wk_s + j * 68 + ci * 4);
            acc[c] += hv.x * wv.x + hv.y * wv.y + hv.z * wv.z + hv.w * wv.w;
        }
    }
    const size_t row = (size_t)n * LL + l;
#pragma unroll
    for (int c = 0; c < 4; ++c) {
        const int col = qd + 16 * c;
        Kmat[row * 64 + col] = acc[c];
        Kh[row * 64 + col] = f2bf(acc[c]);
    }
    // Q row for sample n (threads 0..63)
    if (t < 64) {
        float a = 0.f;
#pragma unroll
        for (int i = 0; i < 64; ++i) a += hs2[15 * 68 + i] * Wq_s[t * 68 + i];
        Qf[(size_t)n * 64 + t] = a;
        Qh[(size_t)n * 64 + t] = f2bf(a);
    }
}

// ---------------------------------------------------------------------------
// Kernel 3: MFMA scores + threshold filter -> candidate emission.
// Grid: 128 q-tiles x 4 row-splits = 512 blocks x 512 threads.
// Per wave: 64 tiles of 16 K-rows. Pass A (8 tiles) -> per-query mu/sigma ->
// theta = mu + 2.6 sigma. Pass B (64 tiles): emit ids with approx score > theta.
// ---------------------------------------------------------------------------
__global__ __launch_bounds__(512) void score_kernel(
    const unsigned short* __restrict__ Kh,  // (32768,64) bf16
    const unsigned short* __restrict__ Qh,  // (2048,64) bf16
    int* __restrict__ cnt,                  // (2048,)
    int* __restrict__ ids)                  // (2048, CAP)
{
    __shared__ float stat_s[8][16];
    __shared__ float stat_q[8][16];
    __shared__ float th_s[16];

    const int t    = threadIdx.x;
    const int wave = t >> 6;
    const int lane = t & 63;
    const int n    = lane & 15;
    const int quad = lane >> 4;

    const int qbase = (blockIdx.x >> 2) * 16;
    const int split = blockIdx.x & 3;
    const int qg    = qbase + n;

    // B fragments (Q), loaded once: k-chunk = ks*32 + quad*8
    FragCast bq0, bq1;
    bq0.u = *(const uint4*)(Qh + (size_t)qg * 64 + 0 * 32 + quad * 8);
    bq1.u = *(const uint4*)(Qh + (size_t)qg * 64 + 1 * 32 + quad * 8);

    const int tile0 = split * 512 + wave * 64;   // this wave's first global tile

    // ---- Pass A: stats over first 8 tiles ----
    float ssum = 0.f, ssq = 0.f;
    {
        FragCast a0, a1, na0, na1;
        const unsigned short* r0 = Kh + (size_t)(tile0 * 16 + n) * 64;
        a0.u = *(const uint4*)(r0 + quad * 8);
        a1.u = *(const uint4*)(r0 + 32 + quad * 8);
        for (int i = 0; i < 8; ++i) {
            if (i + 1 < 8) {
                const unsigned short* r = Kh + (size_t)((tile0 + i + 1) * 16 + n) * 64;
                na0.u = *(const uint4*)(r + quad * 8);
                na1.u = *(const uint4*)(r + 32 + quad * 8);
            }
            floatx4 acc = {0.f, 0.f, 0.f, 0.f};
            acc = __builtin_amdgcn_mfma_f32_16x16x32_bf16(a0.b, bq0.b, acc, 0, 0, 0);
            acc = __builtin_amdgcn_mfma_f32_16x16x32_bf16(a1.b, bq1.b, acc, 0, 0, 0);
#pragma unroll
            for (int j = 0; j < 4; ++j) { ssum += acc[j]; ssq += acc[j] * acc[j]; }
            a0 = na0; a1 = na1;
        }
    }
    // reduce across the 4 quads (lanes n, n+16, n+32, n+48)
    ssum += __shfl_xor(ssum, 16, 64); ssq += __shfl_xor(ssq, 16, 64);
    ssum += __shfl_xor(ssum, 32, 64); ssq += __shfl_xor(ssq, 32, 64);
    if (lane < 16) { stat_s[wave][n] = ssum; stat_q[wave][n] = ssq; }
    __syncthreads();
    if (t < 16) {
        float S = 0.f, S2 = 0.f;
#pragma unroll
        for (int w = 0; w < 8; ++w) { S += stat_s[w][t]; S2 += stat_q[w][t]; }
        const float inv = 1.f / 1024.f;            // 8 waves * 8 tiles * 16 rows
        const float mu = S * inv;
        float var = S2 * inv - mu * mu;
        var = var > 0.f ? var : 0.f;
        th_s[t] = mu + 2.6f * __fsqrt_rn(var);
    }
    __syncthreads();
    const float th = th_s[n];

    // ---- Pass B: full 64 tiles, emit candidates above threshold ----
    int bufid[16];
    int bcnt = 0;
    {
        FragCast a0, a1, na0, na1;
        const unsigned short* r0 = Kh + (size_t)(tile0 * 16 + n) * 64;
        a0.u = *(const uint4*)(r0 + quad * 8);
        a1.u = *(const uint4*)(r0 + 32 + quad * 8);
        for (int i = 0; i < 64; ++i) {
            if (i + 1 < 64) {
                const unsigned short* r = Kh + (size_t)((tile0 + i + 1) * 16 + n) * 64;
                na0.u = *(const uint4*)(r + quad * 8);
                na1.u = *(const uint4*)(r + 32 + quad * 8);
            }
            floatx4 acc = {0.f, 0.f, 0.f, 0.f};
            acc = __builtin_amdgcn_mfma_f32_16x16x32_bf16(a0.b, bq0.b, acc, 0, 0, 0);
            acc = __builtin_amdgcn_mfma_f32_16x16x32_bf16(a1.b, bq1.b, acc, 0, 0, 0);
            const int rowb = (tile0 + i) * 16 + quad * 4;
#pragma unroll
            for (int j = 0; j < 4; ++j) {
                const float s = acc[j];
                const int rowid = rowb + j;
                if (s > th && (rowid >> 4) != qg && bcnt < 16) {
#pragma unroll
                    for (int k = 0; k < 16; ++k) if (k == bcnt) bufid[k] = rowid;
                    bcnt++;
                }
            }
            a0 = na0; a1 = na1;
        }
    }
    // flush buffered candidates to the global per-query list
    if (bcnt > 0) {
        const int base = atomicAdd(&cnt[qg], bcnt);
#pragma unroll
        for (int k = 0; k < 16; ++k) {
            if (k < bcnt) {
                const int slot = base + k;
                if (slot < CAP) ids[(size_t)qg * CAP + slot] = bufid[k];
            }
        }
    }
}

// ---------------------------------------------------------------------------
// Kernel 4: exact fp32 rescore of all candidates + top-10 + softmax + MLP.
// 128 blocks x 256 threads, 16 queries/block.
// ---------------------------------------------------------------------------
__global__ __launch_bounds__(256) void final_kernel(
    const float* __restrict__ x,      // (N,T,F)
    const float* __restrict__ Qf,     // (2048,64)
    const float* __restrict__ Kmat,   // (32768,64)
    const int* __restrict__ cnt,
    const int* __restrict__ ids,
    const float* __restrict__ W1, const float* __restrict__ b1,
    const float* __restrict__ W2, const float* __restrict__ b2,
    float* __restrict__ out)          // (N,)
{
    __shared__ __attribute__((aligned(16))) float Qs[16 * 64];
    __shared__ float sval[16][CAP];   // 60 KB
    __shared__ int cnt_s[16];

    const int t = threadIdx.x;
    const int qbase = blockIdx.x * 16;

    *(float4*)(Qs + t * 4) = *(const float4*)(Qf + (size_t)qbase * 64 + t * 4);
    if (t < 16) {
        int c = cnt[qbase + t];
        cnt_s[t] = c < CAP ? c : CAP;
    }
    __syncthreads();

    for (int q = 0; q < 16; ++q) {
        const int mc = cnt_s[q];
        const float* qr = Qs + q * 64;
        for (int c = t; c < mc; c += 256) {
            const int id = ids[(size_t)(qbase + q) * CAP + c];
            const float* kr = Kmat + (size_t)id * 64;
            float a0 = 0.f, a1 = 0.f, a2 = 0.f, a3 = 0.f;
#pragma unroll
            for (int i = 0; i < 64; i += 4) {
                a0 += qr[i] * kr[i];
                a1 += qr[i + 1] * kr[i + 1];
                a2 += qr[i + 2] * kr[i + 2];
                a3 += qr[i + 3] * kr[i + 3];
            }
            sval[q][c] = (a0 + a1) + (a2 + a3);
        }
    }
    __syncthreads();

    if (t < 16) {
        const int q = t, mc = cnt_s[q];
        float v[TOPKK]; int vid[TOPKK];
#pragma unroll
        for (int r = 0; r < TOPKK; ++r) { v[r] = -3e38f; vid[r] = -1; }
        float vmin = -3e38f; int imin = 0;
        for (int c = 0; c < mc; ++c) {
            const float s = sval[q][c];
            if (s > vmin) {
                const int id = ids[(size_t)(qbase + q) * CAP + c];
#pragma unroll
                for (int r = 0; r < TOPKK; ++r) if (r == imin) { v[r] = s; vid[r] = id; }
                vmin = v[0]; imin = 0;
#pragma unroll
                for (int r = 1; r < TOPKK; ++r) if (v[r] < vmin) { vmin = v[r]; imin = r; }
            }
        }
        float mx = v[0];
#pragma unroll
        for (int r = 1; r < TOPKK; ++r) mx = v[r] > mx ? v[r] : mx;
        float w[TOPKK]; float sum = 0.f;
#pragma unroll
        for (int r = 0; r < TOPKK; ++r) { w[r] = __expf(v[r] - mx); sum += w[r]; }
        const float inv = 1.f / sum;
        float feat[FF];
#pragma unroll
        for (int f = 0; f < FF; ++f) feat[f] = 0.f;
        for (int r = 0; r < TOPKK; ++r) {
            const int wi = vid[r];
            const int m = wi >> 4, l = wi & 15;
            const float* xr = x + ((size_t)m * TT + (48 + l)) * FF;
            const float wr = w[r] * inv;
#pragma unroll
            for (int f = 0; f < FF; ++f) feat[f] += wr * xr[f];
        }
        float o = 0.f;
#pragma unroll
        for (int oo = 0; oo < FF; ++oo) {
            float hh = b1[oo];
#pragma unroll
            for (int f = 0; f < FF; ++f) hh += feat[f] * W1[oo * FF + f];
            hh = hh > 0.f ? hh : 0.01f * hh;
            o += hh * W2[oo];
        }
        o += b2[0];
        out[qbase + q] = o;
    }
}

// ---------------------------------------------------------------------------
extern "C" void kernel_launch(void* const* d_in, const int* in_sizes, int n_in,
                              void* d_out, int out_size, void* d_ws, size_t ws_size,
                              hipStream_t stream) {
    const float* x    = (const float*)d_in[0];
    const float* W_ih = (const float*)d_in[1];
    const float* W_hh = (const float*)d_in[2];
    const float* b_ih = (const float*)d_in[3];
    const float* b_hh = (const float*)d_in[4];
    const float* Wq   = (const float*)d_in[5];
    const float* Wk   = (const float*)d_in[6];
    const float* W1   = (const float*)d_in[7];
    const float* b1   = (const float*)d_in[8];
    const float* W2   = (const float*)d_in[9];
    const float* b2   = (const float*)d_in[10];
    float* outp = (float*)d_out;
    (void)ws_size; (void)n_in; (void)in_sizes; (void)out_size;

    // ws layout (h_tail is consumed by prep; ids overlay it afterwards)
    float* h_tail        = (float*)d_ws;                               // 2048*16*64 f32 = 8 MB
    int*   ids           = (int*)d_ws;                                 // 2048*CAP ints = 7.86 MB (overlay)
    float* Kmat          = h_tail + (size_t)2048 * 1024;               // 8 MB
    unsigned short* Kh   = (unsigned short*)(Kmat + (size_t)32768 * 64); // 4 MB
    float* Qf            = (float*)(Kh + (size_t)32768 * 64);          // 0.5 MB
    unsigned short* Qh   = (unsigned short*)(Qf + (size_t)2048 * 64);  // 0.25 MB
    int*   cnt           = (int*)(Qh + (size_t)2048 * 64);             // 8 KB

    hipMemsetAsync(cnt, 0, 2048 * sizeof(int), stream);
    gru_kernel<<<NN / 4, 128, 0, stream>>>(x, W_ih, W_hh, b_ih, b_hh, h_tail);
    prep_kernel<<<NN, 256, 0, stream>>>(h_tail, Wk, Wq, Kmat, Kh, Qf, Qh);
    score_kernel<<<512, 512, 0, stream>>>(Kh, Qh, cnt, ids);
    final_kernel<<<NN / 16, 256, 0, stream>>>(x, Qf, Kmat, cnt, ids, W1, b1, W2, b2, outp);
}

// Round 4
// 360.376 us; speedup vs baseline: 2.1536x; 1.2732x over previous
//
#include <hip/hip_runtime.h>

#define NN 2048
#define TT 64
#define FF 16
#define HH 64
#define LL 16
#define TOPKK 10
#define CAP 960
#define SB 8            // samples per GRU block

typedef __bf16 bf16x8 __attribute__((ext_vector_type(8)));
typedef float floatx4 __attribute__((ext_vector_type(4)));

union FragCast { uint4 u; bf16x8 b; unsigned short s[8]; };

__device__ __forceinline__ unsigned short f2bf(float f) {
    unsigned u = __float_as_uint(f);
    return (unsigned short)((u + 0x7fff + ((u >> 16) & 1)) >> 16);
}
__device__ __forceinline__ float bf2f(unsigned short h) {
    return __uint_as_float(((unsigned)h) << 16);
}
__device__ __forceinline__ void split3(float v, unsigned short& a, unsigned short& b, unsigned short& c) {
    a = f2bf(v); float r = v - bf2f(a);
    b = f2bf(r); float r2 = r - bf2f(b);
    c = f2bf(r2);
}

// ---------------------------------------------------------------------------
// Kernel 1: MFMA GRU. 256 blocks x 256 threads (4 waves), 8 samples/block.
// Per step: one fused GEMM  [h(64) | x_t(16) | 0-pad] @ [W_hh | W_ih]^T
// via mfma_f32_16x16x32_bf16 with 3-limb bf16 emulation (6 products) ->
// ~fp32 accuracy. W fragments register-resident (loaded once).
// A-operand limbs (h,x splits) live in LDS, rewritten each step.
// n-gate tiles (rows 128..191) keep h-part and x-part in separate
// accumulators because r multiplies only the h-part.
// ---------------------------------------------------------------------------
__global__ __launch_bounds__(256, 1) void gru_kernel(
    const float* __restrict__ x,      // (N,T,F)
    const float* __restrict__ W_ih,   // (192,16)
    const float* __restrict__ W_hh,   // (192,64)
    const float* __restrict__ b_ih,   // (192,)
    const float* __restrict__ b_hh,   // (192,)
    float* __restrict__ h_tail)       // (N,16,64)
{
    __shared__ __attribute__((aligned(16))) unsigned short Asp[3][16 * 104]; // bf16 limb planes, K padded to 96 (cols 80..95 stay 0)
    __shared__ __attribute__((aligned(16))) float pre[16 * 260]; // [sample][col]: 0..127 rz, 128..191 hn, 192..255 xn
    __shared__ __attribute__((aligned(16))) float h_f[SB * 68];  // fp32 master h

    const int t    = threadIdx.x;
    const int wv   = t >> 6;
    const int lane = t & 63;
    const int nh   = lane & 15;
    const int quad = lane >> 4;
    const int n0   = blockIdx.x * SB;

    // zero LDS (sample rows 8..15 and K-cols 80..95 must stay zero forever)
    for (int i = t; i < 3 * 16 * 104; i += 256) (&Asp[0][0])[i] = 0;
    for (int i = t; i < SB * 68; i += 256) h_f[i] = 0.f;

    // per-thread gate biases (j = t&63)
    const int jb = t & 63;
    const float brz = b_ih[jb] + b_hh[jb];
    const float bz  = b_ih[64 + jb] + b_hh[64 + jb];
    const float bxn = b_ih[128 + jb];
    const float bhn = b_hh[128 + jb];

    // W fragments: wave wv owns N-tiles 3wv..3wv+2 (gate rows 48wv..48wv+47).
    // B[k][n]: lane nh = gate row within tile, k = kc*32 + quad*8 + j.
    // k<64 -> W_hh, 64<=k<80 -> W_ih, k>=80 -> 0.
    bf16x8 wf[3][3][3];
#pragma unroll
    for (int nt = 0; nt < 3; ++nt) {
        const int gr = (3 * wv + nt) * 16 + nh;
#pragma unroll
        for (int kc = 0; kc < 3; ++kc) {
            float v[8];
            if (kc < 2) {
                const float* p = W_hh + gr * 64 + kc * 32 + quad * 8;
#pragma unroll
                for (int i = 0; i < 8; ++i) v[i] = p[i];
            } else if (quad < 2) {
                const float* p = W_ih + gr * 16 + quad * 8;
#pragma unroll
                for (int i = 0; i < 8; ++i) v[i] = p[i];
            } else {
#pragma unroll
                for (int i = 0; i < 8; ++i) v[i] = 0.f;
            }
            FragCast f1, f2, f3;
#pragma unroll
            for (int i = 0; i < 8; ++i) split3(v[i], f1.s[i], f2.s[i], f3.s[i]);
            wf[nt][kc][0] = f1.b; wf[nt][kc][1] = f2.b; wf[nt][kc][2] = f3.b;
        }
    }

    const int sx = t >> 4, fx = t & 15;   // x-staging role (threads 0..127)
    __syncthreads();                      // zeros visible before x-limb writes
    if (t < 128) {
        const float xc = x[((size_t)(n0 + sx) * TT + 0) * FF + fx];
        unsigned short a, b, c; split3(xc, a, b, c);
        Asp[0][sx * 104 + 64 + fx] = a;
        Asp[1][sx * 104 + 64 + fx] = b;
        Asp[2][sx * 104 + 64 + fx] = c;
    }
    __syncthreads();

    for (int step = 0; step < TT; ++step) {
        // prefetch next step's x during the GEMM phase
        float xnext = 0.f;
        if (t < 128) {
            const int ts = step < TT - 1 ? step + 1 : TT - 1;
            xnext = x[((size_t)(n0 + sx) * TT + ts) * FF + fx];
        }

        floatx4 acc[3]  = {{0.f,0.f,0.f,0.f},{0.f,0.f,0.f,0.f},{0.f,0.f,0.f,0.f}};
        floatx4 accx[3] = {{0.f,0.f,0.f,0.f},{0.f,0.f,0.f,0.f},{0.f,0.f,0.f,0.f}};
#pragma unroll
        for (int kc = 0; kc < 3; ++kc) {
            FragCast a1, a2, a3;   // A[m=nh][k]: limb planes, shared across this wave's 3 N-tiles
            a1.u = *(const uint4*)&Asp[0][nh * 104 + kc * 32 + quad * 8];
            a2.u = *(const uint4*)&Asp[1][nh * 104 + kc * 32 + quad * 8];
            a3.u = *(const uint4*)&Asp[2][nh * 104 + kc * 32 + quad * 8];
#pragma unroll
            for (int nt = 0; nt < 3; ++nt) {
                const bool xpart = (3 * wv + nt >= 8) && (kc == 2);
                floatx4 A = xpart ? accx[nt] : acc[nt];
                A = __builtin_amdgcn_mfma_f32_16x16x32_bf16(a1.b, wf[nt][kc][0], A, 0, 0, 0);
                A = __builtin_amdgcn_mfma_f32_16x16x32_bf16(a1.b, wf[nt][kc][1], A, 0, 0, 0);
                A = __builtin_amdgcn_mfma_f32_16x16x32_bf16(a2.b, wf[nt][kc][0], A, 0, 0, 0);
                A = __builtin_amdgcn_mfma_f32_16x16x32_bf16(a1.b, wf[nt][kc][2], A, 0, 0, 0);
                A = __builtin_amdgcn_mfma_f32_16x16x32_bf16(a2.b, wf[nt][kc][1], A, 0, 0, 0);
                A = __builtin_amdgcn_mfma_f32_16x16x32_bf16(a3.b, wf[nt][kc][0], A, 0, 0, 0);
                if (xpart) accx[nt] = A; else acc[nt] = A;
            }
        }
        // write preactivations: D element (sample = quad*4+r, gate col = tile*16+nh)
#pragma unroll
        for (int nt = 0; nt < 3; ++nt) {
            const int gtile = 3 * wv + nt;
            const int gr = gtile * 16 + nh;
#pragma unroll
            for (int r = 0; r < 4; ++r) {
                const int srow = quad * 4 + r;
                pre[srow * 260 + gr] = acc[nt][r];
                if (gtile >= 8) pre[srow * 260 + 64 + gr] = accx[nt][r];
            }
        }
        __syncthreads();

        // pointwise gates: 2 units per thread (s = t>>6 + 4*cs, j = t&63)
#pragma unroll
        for (int cs = 0; cs < 2; ++cs) {
            const int s = (t >> 6) + 4 * cs;
            const float rp = pre[s * 260 + jb] + brz;
            const float zp = pre[s * 260 + 64 + jb] + bz;
            const float hn = pre[s * 260 + 128 + jb] + bhn;
            const float xn = pre[s * 260 + 192 + jb] + bxn;
            const float r = 1.f / (1.f + expf(-rp));
            const float z = 1.f / (1.f + expf(-zp));
            const float nn = tanhf(xn + r * hn);
            const float hold = h_f[s * 68 + jb];
            const float hnew = (1.f - z) * nn + z * hold;
            h_f[s * 68 + jb] = hnew;
            unsigned short a, b, c; split3(hnew, a, b, c);
            Asp[0][s * 104 + jb] = a;
            Asp[1][s * 104 + jb] = b;
            Asp[2][s * 104 + jb] = c;
            if (step >= TT - LL)
                h_tail[((size_t)(n0 + s) * LL + (step - (TT - LL))) * HH + jb] = hnew;
        }
        if (t < 128) {   // stage next x limbs
            unsigned short a, b, c; split3(xnext, a, b, c);
            Asp[0][sx * 104 + 64 + fx] = a;
            Asp[1][sx * 104 + 64 + fx] = b;
            Asp[2][sx * 104 + 64 + fx] = c;
        }
        __syncthreads();
    }
}

// ---------------------------------------------------------------------------
// Kernel 2: prep (unchanged from R3). K rows + Q rows, fp32 + bf16.
// ---------------------------------------------------------------------------
__global__ __launch_bounds__(256) void prep_kernel(
    const float* __restrict__ h_tail, // (N,16,64)
    const float* __restrict__ Wk,     // (64,64)
    const float* __restrict__ Wq,     // (64,64)
    float* __restrict__ Kmat,         // (32768,64) fp32
    unsigned short* __restrict__ Kh,  // (32768,64) bf16
    float* __restrict__ Qf,           // (2048,64) fp32
    unsigned short* __restrict__ Qh)  // (2048,64) bf16
{
    __shared__ __attribute__((aligned(16))) float Wk_s[64 * 68];
    __shared__ __attribute__((aligned(16))) float Wq_s[64 * 68];
    __shared__ __attribute__((aligned(16))) float hs2[16 * 68];
    const int t = threadIdx.x;
    const int n = blockIdx.x;

    for (int c = t; c < 1024; c += 256) {
        const int j = c >> 4, ci = c & 15;
        *(float4*)(Wk_s + j * 68 + ci * 4) = *(const float4*)(Wk + c * 4);
        *(float4*)(Wq_s + j * 68 + ci * 4) = *(const float4*)(Wq + c * 4);
    }
    {
        const int l = t >> 4, ci = t & 15;
        *(float4*)(hs2 + l * 68 + ci * 4) = *(const float4*)(h_tail + (size_t)n * 1024 + t * 4);
    }
    __syncthreads();

    const int l = t >> 4, qd = t & 15;
    float acc[4] = {0.f, 0.f, 0.f, 0.f};
#pragma unroll
    for (int ci = 0; ci < 16; ++ci) {
        const float4 hv = *(const float4*)(hs2 + l * 68 + ci * 4);
#pragma unroll
        for (int c = 0; c < 4; ++c) {
            const int j = qd + 16 * c;
            const float4 wv = *(const float4*)(Wk_s + j * 68 + ci * 4);
            acc[c] += hv.x * wv.x + hv.y * wv.y + hv.z * wv.z + hv.w * wv.w;
        }
    }
    const size_t row = (size_t)n * LL + l;
#pragma unroll
    for (int c = 0; c < 4; ++c) {
        const int col = qd + 16 * c;
        Kmat[row * 64 + col] = acc[c];
        Kh[row * 64 + col] = f2bf(acc[c]);
    }
    if (t < 64) {
        float a = 0.f;
#pragma unroll
        for (int i = 0; i < 64; ++i) a += hs2[15 * 68 + i] * Wq_s[t * 68 + i];
        Qf[(size_t)n * 64 + t] = a;
        Qh[(size_t)n * 64 + t] = f2bf(a);
    }
}

// ---------------------------------------------------------------------------
// Kernel 3: MFMA scores + threshold filter -> candidate emission (unchanged).
// ---------------------------------------------------------------------------
__global__ __launch_bounds__(512) void score_kernel(
    const unsigned short* __restrict__ Kh,  // (32768,64) bf16
    const unsigned short* __restrict__ Qh,  // (2048,64) bf16
    int* __restrict__ cnt,                  // (2048,)
    int* __restrict__ ids)                  // (2048, CAP)
{
    __shared__ float stat_s[8][16];
    __shared__ float stat_q[8][16];
    __shared__ float th_s[16];

    const int t    = threadIdx.x;
    const int wave = t >> 6;
    const int lane = t & 63;
    const int n    = lane & 15;
    const int quad = lane >> 4;

    const int qbase = (blockIdx.x >> 2) * 16;
    const int split = blockIdx.x & 3;
    const int qg    = qbase + n;

    FragCast bq0, bq1;
    bq0.u = *(const uint4*)(Qh + (size_t)qg * 64 + 0 * 32 + quad * 8);
    bq1.u = *(const uint4*)(Qh + (size_t)qg * 64 + 1 * 32 + quad * 8);

    const int tile0 = split * 512 + wave * 64;

    // Pass A: stats over first 8 tiles
    float ssum = 0.f, ssq = 0.f;
    {
        FragCast a0, a1, na0, na1;
        const unsigned short* r0 = Kh + (size_t)(tile0 * 16 + n) * 64;
        a0.u = *(const uint4*)(r0 + quad * 8);
        a1.u = *(const uint4*)(r0 + 32 + quad * 8);
        for (int i = 0; i < 8; ++i) {
            if (i + 1 < 8) {
                const unsigned short* r = Kh + (size_t)((tile0 + i + 1) * 16 + n) * 64;
                na0.u = *(const uint4*)(r + quad * 8);
                na1.u = *(const uint4*)(r + 32 + quad * 8);
            }
            floatx4 acc = {0.f, 0.f, 0.f, 0.f};
            acc = __builtin_amdgcn_mfma_f32_16x16x32_bf16(a0.b, bq0.b, acc, 0, 0, 0);
            acc = __builtin_amdgcn_mfma_f32_16x16x32_bf16(a1.b, bq1.b, acc, 0, 0, 0);
#pragma unroll
            for (int j = 0; j < 4; ++j) { ssum += acc[j]; ssq += acc[j] * acc[j]; }
            a0 = na0; a1 = na1;
        }
    }
    ssum += __shfl_xor(ssum, 16, 64); ssq += __shfl_xor(ssq, 16, 64);
    ssum += __shfl_xor(ssum, 32, 64); ssq += __shfl_xor(ssq, 32, 64);
    if (lane < 16) { stat_s[wave][n] = ssum; stat_q[wave][n] = ssq; }
    __syncthreads();
    if (t < 16) {
        float S = 0.f, S2 = 0.f;
#pragma unroll
        for (int w = 0; w < 8; ++w) { S += stat_s[w][t]; S2 += stat_q[w][t]; }
        const float inv = 1.f / 1024.f;
        const float mu = S * inv;
        float var = S2 * inv - mu * mu;
        var = var > 0.f ? var : 0.f;
        th_s[t] = mu + 2.6f * __fsqrt_rn(var);
    }
    __syncthreads();
    const float th = th_s[n];

    // Pass B: full 64 tiles, emit candidates above threshold
    int bufid[16];
    int bcnt = 0;
    {
        FragCast a0, a1, na0, na1;
        const unsigned short* r0 = Kh + (size_t)(tile0 * 16 + n) * 64;
        a0.u = *(const uint4*)(r0 + quad * 8);
        a1.u = *(const uint4*)(r0 + 32 + quad * 8);
        for (int i = 0; i < 64; ++i) {
            if (i + 1 < 64) {
                const unsigned short* r = Kh + (size_t)((tile0 + i + 1) * 16 + n) * 64;
                na0.u = *(const uint4*)(r + quad * 8);
                na1.u = *(const uint4*)(r + 32 + quad * 8);
            }
            floatx4 acc = {0.f, 0.f, 0.f, 0.f};
            acc = __builtin_amdgcn_mfma_f32_16x16x32_bf16(a0.b, bq0.b, acc, 0, 0, 0);
            acc = __builtin_amdgcn_mfma_f32_16x16x32_bf16(a1.b, bq1.b, acc, 0, 0, 0);
            const int rowb = (tile0 + i) * 16 + quad * 4;
#pragma unroll
            for (int j = 0; j < 4; ++j) {
                const float s = acc[j];
                const int rowid = rowb + j;
                if (s > th && (rowid >> 4) != qg && bcnt < 16) {
#pragma unroll
                    for (int k = 0; k < 16; ++k) if (k == bcnt) bufid[k] = rowid;
                    bcnt++;
                }
            }
            a0 = na0; a1 = na1;
        }
    }
    if (bcnt > 0) {
        const int base = atomicAdd(&cnt[qg], bcnt);
#pragma unroll
        for (int k = 0; k < 16; ++k) {
            if (k < bcnt) {
                const int slot = base + k;
                if (slot < CAP) ids[(size_t)qg * CAP + slot] = bufid[k];
            }
        }
    }
}

// ---------------------------------------------------------------------------
// Kernel 4: exact fp32 rescore + top-10 + softmax + MLP (unchanged).
// ---------------------------------------------------------------------------
__global__ __launch_bounds__(256) void final_kernel(
    const float* __restrict__ x,      // (N,T,F)
    const float* __restrict__ Qf,     // (2048,64)
    const float* __restrict__ Kmat,   // (32768,64)
    const int* __restrict__ cnt,
    const int* __restrict__ ids,
    const float* __restrict__ W1, const float* __restrict__ b1,
    const float* __restrict__ W2, const float* __restrict__ b2,
    float* __restrict__ out)          // (N,)
{
    __shared__ __attribute__((aligned(16))) float Qs[16 * 64];
    __shared__ float sval[16][CAP];
    __shared__ int cnt_s[16];

    const int t = threadIdx.x;
    const int qbase = blockIdx.x * 16;

    *(float4*)(Qs + t * 4) = *(const float4*)(Qf + (size_t)qbase * 64 + t * 4);
    if (t < 16) {
        int c = cnt[qbase + t];
        cnt_s[t] = c < CAP ? c : CAP;
    }
    __syncthreads();

    for (int q = 0; q < 16; ++q) {
        const int mc = cnt_s[q];
        const float* qr = Qs + q * 64;
        for (int c = t; c < mc; c += 256) {
            const int id = ids[(size_t)(qbase + q) * CAP + c];
            const float* kr = Kmat + (size_t)id * 64;
            float a0 = 0.f, a1 = 0.f, a2 = 0.f, a3 = 0.f;
#pragma unroll
            for (int i = 0; i < 64; i += 4) {
                a0 += qr[i] * kr[i];
                a1 += qr[i + 1] * kr[i + 1];
                a2 += qr[i + 2] * kr[i + 2];
                a3 += qr[i + 3] * kr[i + 3];
            }
            sval[q][c] = (a0 + a1) + (a2 + a3);
        }
    }
    __syncthreads();

    if (t < 16) {
        const int q = t, mc = cnt_s[q];
        float v[TOPKK]; int vid[TOPKK];
#pragma unroll
        for (int r = 0; r < TOPKK; ++r) { v[r] = -3e38f; vid[r] = -1; }
        float vmin = -3e38f; int imin = 0;
        for (int c = 0; c < mc; ++c) {
            const float s = sval[q][c];
            if (s > vmin) {
                const int id = ids[(size_t)(qbase + q) * CAP + c];
#pragma unroll
                for (int r = 0; r < TOPKK; ++r) if (r == imin) { v[r] = s; vid[r] = id; }
                vmin = v[0]; imin = 0;
#pragma unroll
                for (int r = 1; r < TOPKK; ++r) if (v[r] < vmin) { vmin = v[r]; imin = r; }
            }
        }
        float mx = v[0];
#pragma unroll
        for (int r = 1; r < TOPKK; ++r) mx = v[r] > mx ? v[r] : mx;
        float w[TOPKK]; float sum = 0.f;
#pragma unroll
        for (int r = 0; r < TOPKK; ++r) { w[r] = __expf(v[r] - mx); sum += w[r]; }
        const float inv = 1.f / sum;
        float feat[FF];
#pragma unroll
        for (int f = 0; f < FF; ++f) feat[f] = 0.f;
        for (int r = 0; r < TOPKK; ++r) {
            const int wi = vid[r];
            const int m = wi >> 4, l = wi & 15;
            const float* xr = x + ((size_t)m * TT + (48 + l)) * FF;
            const float wr = w[r] * inv;
#pragma unroll
            for (int f = 0; f < FF; ++f) feat[f] += wr * xr[f];
        }
        float o = 0.f;
#pragma unroll
        for (int oo = 0; oo < FF; ++oo) {
            float hh = b1[oo];
#pragma unroll
            for (int f = 0; f < FF; ++f) hh += feat[f] * W1[oo * FF + f];
            hh = hh > 0.f ? hh : 0.01f * hh;
            o += hh * W2[oo];
        }
        o += b2[0];
        out[qbase + q] = o;
    }
}

// ---------------------------------------------------------------------------
extern "C" void kernel_launch(void* const* d_in, const int* in_sizes, int n_in,
                              void* d_out, int out_size, void* d_ws, size_t ws_size,
                              hipStream_t stream) {
    const float* x    = (const float*)d_in[0];
    const float* W_ih = (const float*)d_in[1];
    const float* W_hh = (const float*)d_in[2];
    const float* b_ih = (const float*)d_in[3];
    const float* b_hh = (const float*)d_in[4];
    const float* Wq   = (const float*)d_in[5];
    const float* Wk   = (const float*)d_in[6];
    const float* W1   = (const float*)d_in[7];
    const float* b1   = (const float*)d_in[8];
    const float* W2   = (const float*)d_in[9];
    const float* b2   = (const float*)d_in[10];
    float* outp = (float*)d_out;
    (void)ws_size; (void)n_in; (void)in_sizes; (void)out_size;

    float* h_tail        = (float*)d_ws;                               // 8 MB
    int*   ids           = (int*)d_ws;                                 // overlay (after prep consumes h_tail)
    float* Kmat          = h_tail + (size_t)2048 * 1024;               // 8 MB
    unsigned short* Kh   = (unsigned short*)(Kmat + (size_t)32768 * 64); // 4 MB
    float* Qf            = (float*)(Kh + (size_t)32768 * 64);          // 0.5 MB
    unsigned short* Qh   = (unsigned short*)(Qf + (size_t)2048 * 64);  // 0.25 MB
    int*   cnt           = (int*)(Qh + (size_t)2048 * 64);             // 8 KB

    hipMemsetAsync(cnt, 0, 2048 * sizeof(int), stream);
    gru_kernel<<<NN / SB, 256, 0, stream>>>(x, W_ih, W_hh, b_ih, b_hh, h_tail);
    prep_kernel<<<NN, 256, 0, stream>>>(h_tail, Wk, Wq, Kmat, Kh, Qf, Qh);
    score_kernel<<<512, 512, 0, stream>>>(Kh, Qh, cnt, ids);
    final_kernel<<<NN / 16, 256, 0, stream>>>(x, Qf, Kmat, cnt, ids, W1, b1, W2, b2, outp);
}

// Round 5
// 324.507 us; speedup vs baseline: 2.3917x; 1.1105x over previous
//
#include <hip/hip_runtime.h>

#define NN 2048
#define TT 64
#define FF 16
#define HH 64
#define LL 16
#define TOPKK 10
#define CAP 960

typedef __bf16 bf16x8 __attribute__((ext_vector_type(8)));
typedef float floatx4 __attribute__((ext_vector_type(4)));

union FragCast { uint4 u; bf16x8 b; unsigned short s[8]; };

__device__ __forceinline__ unsigned short f2bf(float f) {
    unsigned u = __float_as_uint(f);
    return (unsigned short)((u + 0x7fff + ((u >> 16) & 1)) >> 16);
}
__device__ __forceinline__ float bf2f(unsigned short h) {
    return __uint_as_float(((unsigned)h) << 16);
}
__device__ __forceinline__ void split3(float v, unsigned short& a, unsigned short& b, unsigned short& c) {
    a = f2bf(v); float r = v - bf2f(a);
    b = f2bf(r); float r2 = r - bf2f(b);
    c = f2bf(r2);
}
// hardware-pipe sigmoid/tanh (v_exp_f32 + v_rcp_f32, ~1 ulp each)
__device__ __forceinline__ float fsigmoid(float x) {
    return __builtin_amdgcn_rcpf(1.f + __builtin_amdgcn_exp2f(-1.442695041f * x));
}
__device__ __forceinline__ float ftanh(float x) {
    return 1.f - 2.f * __builtin_amdgcn_rcpf(1.f + __builtin_amdgcn_exp2f(2.885390082f * x));
}
__device__ __forceinline__ void async_copy16(const void* g, void* l) {
    __builtin_amdgcn_global_load_lds(
        (const __attribute__((address_space(1))) unsigned int*)g,
        (__attribute__((address_space(3))) unsigned int*)l, 16, 0, 0);
}
#define MFMA16(A, B, C) __builtin_amdgcn_mfma_f32_16x16x32_bf16((A), (B), (C), 0, 0, 0)

// ---------------------------------------------------------------------------
// Kernel 1: MFMA GRU v2. 512 blocks x 256 threads (4 waves), 4 samples/block
// -> 2 blocks/CU (TLP). Wave wv owns N-tiles {wv, 4+wv, 8+wv} so each lane
// holds r/z/hn/xn preacts for its own (sample, gate-col): pointwise is fully
// in registers, ONE barrier/step, double-buffered bf16 limb planes in LDS.
// 3-limb bf16 emulation (6 MFMA products) ~ fp32 accuracy. x preloaded to LDS.
// ---------------------------------------------------------------------------
__global__ __launch_bounds__(256, 2) void gru_kernel(
    const float* __restrict__ x,      // (N,T,F)
    const float* __restrict__ W_ih,   // (192,16)
    const float* __restrict__ W_hh,   // (192,64)
    const float* __restrict__ b_ih,   // (192,)
    const float* __restrict__ b_hh,   // (192,)
    float* __restrict__ h_tail)       // (N,16,64)
{
    // limb planes: [buf][limb][m(16) x k(104)] (k: 0..63 h, 64..79 x, 80..95 pad, stride 104)
    __shared__ __attribute__((aligned(16))) unsigned short Asp[2][3][16 * 104]; // ~20 KB
    __shared__ __attribute__((aligned(16))) float x_lds[4 * TT * FF];           // 16 KB

    const int t    = threadIdx.x;
    const int wv   = t >> 6;
    const int lane = t & 63;
    const int nh   = lane & 15;
    const int quad = lane >> 4;
    const int n0   = blockIdx.x * 4;

    // preload this block's x (16 KB contiguous) into LDS
    {
        const char* src = (const char*)(x + (size_t)n0 * TT * FF);
        char* dst = (char*)x_lds;
#pragma unroll
        for (int i = 0; i < 4; ++i)
            async_copy16(src + i * 4096 + t * 16, dst + i * 4096 + t * 16);
    }
    // zero both limb-plane buffers (h0 = 0; pad rows/cols stay 0 forever)
    {
        unsigned* p = (unsigned*)&Asp[0][0][0];
        for (int i = t; i < 2 * 3 * 16 * 104 / 2; i += 256) p[i] = 0;
    }

    // biases for this lane's gate column j = 16*wv + nh (used by quad 0 only)
    const int jb = wv * 16 + nh;
    const float brz = b_ih[jb] + b_hh[jb];
    const float bz  = b_ih[64 + jb] + b_hh[64 + jb];
    const float bxn = b_ih[128 + jb];
    const float bhn = b_hh[128 + jb];

    // W fragments (register-resident): wave wv, tiles {wv, 4+wv, 8+wv}.
    // B[k][n]: n = nh (gate row in tile), k = kc*32 + quad*8 + i.
    bf16x8 wf[3][3][3];
#pragma unroll
    for (int nt = 0; nt < 3; ++nt) {
        const int gr = (wv + 4 * nt) * 16 + nh;
#pragma unroll
        for (int kc = 0; kc < 3; ++kc) {
            float v[8];
            if (kc < 2) {
                const float* p = W_hh + gr * 64 + kc * 32 + quad * 8;
#pragma unroll
                for (int i = 0; i < 8; ++i) v[i] = p[i];
            } else if (quad < 2) {
                const float* p = W_ih + gr * 16 + quad * 8;
#pragma unroll
                for (int i = 0; i < 8; ++i) v[i] = p[i];
            } else {
#pragma unroll
                for (int i = 0; i < 8; ++i) v[i] = 0.f;
            }
            FragCast f1, f2, f3;
#pragma unroll
            for (int i = 0; i < 8; ++i) split3(v[i], f1.s[i], f2.s[i], f3.s[i]);
            wf[nt][kc][0] = f1.b; wf[nt][kc][1] = f2.b; wf[nt][kc][2] = f3.b;
        }
    }

    __syncthreads();   // x_lds ready (vmcnt drained), zeros visible

    // stage step-0 x limbs into buffer 0 (threads 192..255: s = idx>>4, f = idx&15)
    if (t >= 192) {
        const int idx = t - 192, s = idx >> 4, fx = idx & 15;
        unsigned short a, b, c; split3(x_lds[s * (TT * FF) + fx], a, b, c);
        Asp[0][0][s * 104 + 64 + fx] = a;
        Asp[0][1][s * 104 + 64 + fx] = b;
        Asp[0][2][s * 104 + 64 + fx] = c;
    }
    __syncthreads();

    float hprev[4] = {0.f, 0.f, 0.f, 0.f};

    for (int step = 0; step < TT; ++step) {
        const int rb = step & 1, wb = rb ^ 1;
        floatx4 acc0 = {0.f,0.f,0.f,0.f}, acc1 = {0.f,0.f,0.f,0.f};
        floatx4 acc2 = {0.f,0.f,0.f,0.f}, accx = {0.f,0.f,0.f,0.f};

#pragma unroll
        for (int kc = 0; kc < 3; ++kc) {
            const int aoff = nh * 104 + kc * 32 + quad * 8;
            FragCast a1, a2, a3;
            a1.u = *(const uint4*)&Asp[rb][0][aoff];
            a2.u = *(const uint4*)&Asp[rb][1][aoff];
            a3.u = *(const uint4*)&Asp[rb][2][aoff];
#pragma unroll
            for (int nt = 0; nt < 3; ++nt) {
                floatx4 A = (nt == 2 && kc == 2) ? accx : (nt == 0 ? acc0 : nt == 1 ? acc1 : acc2);
                A = MFMA16(a1.b, wf[nt][kc][0], A);
                A = MFMA16(a1.b, wf[nt][kc][1], A);
                A = MFMA16(a2.b, wf[nt][kc][0], A);
                A = MFMA16(a1.b, wf[nt][kc][2], A);
                A = MFMA16(a2.b, wf[nt][kc][1], A);
                A = MFMA16(a3.b, wf[nt][kc][0], A);
                if (nt == 2 && kc == 2) accx = A;
                else if (nt == 0) acc0 = A;
                else if (nt == 1) acc1 = A;
                else acc2 = A;
            }
        }

        // pointwise in registers (quad 0 lanes hold samples 0..3 = D rows 0..3)
        if (quad == 0) {
#pragma unroll
            for (int r = 0; r < 4; ++r) {
                const float rp = acc0[r] + brz;
                const float zp = acc1[r] + bz;
                const float hn = acc2[r] + bhn;
                const float xn = accx[r] + bxn;
                const float rg = fsigmoid(rp);
                const float zg = fsigmoid(zp);
                const float ng = ftanh(xn + rg * hn);
                const float h  = (1.f - zg) * ng + zg * hprev[r];
                hprev[r] = h;
                unsigned short la, lb2, lc; split3(h, la, lb2, lc);
                Asp[wb][0][r * 104 + jb] = la;
                Asp[wb][1][r * 104 + jb] = lb2;
                Asp[wb][2][r * 104 + jb] = lc;
                if (step >= TT - LL)
                    h_tail[((size_t)(n0 + r) * LL + (step - (TT - LL))) * HH + jb] = h;
            }
        }
        // stage next step's x limbs into the write buffer
        if (t >= 192 && step + 1 < TT) {
            const int idx = t - 192, s = idx >> 4, fx = idx & 15;
            unsigned short a, b, c; split3(x_lds[s * (TT * FF) + (step + 1) * FF + fx], a, b, c);
            Asp[wb][0][s * 104 + 64 + fx] = a;
            Asp[wb][1][s * 104 + 64 + fx] = b;
            Asp[wb][2][s * 104 + 64 + fx] = c;
        }
        __syncthreads();   // single barrier per step (double-buffered WAR-free)
    }
}

// ---------------------------------------------------------------------------
// Kernel 2: prep (unchanged). K rows + Q rows, fp32 + bf16.
// ---------------------------------------------------------------------------
__global__ __launch_bounds__(256) void prep_kernel(
    const float* __restrict__ h_tail, // (N,16,64)
    const float* __restrict__ Wk,     // (64,64)
    const float* __restrict__ Wq,     // (64,64)
    float* __restrict__ Kmat,         // (32768,64) fp32
    unsigned short* __restrict__ Kh,  // (32768,64) bf16
    float* __restrict__ Qf,           // (2048,64) fp32
    unsigned short* __restrict__ Qh)  // (2048,64) bf16
{
    __shared__ __attribute__((aligned(16))) float Wk_s[64 * 68];
    __shared__ __attribute__((aligned(16))) float Wq_s[64 * 68];
    __shared__ __attribute__((aligned(16))) float hs2[16 * 68];
    const int t = threadIdx.x;
    const int n = blockIdx.x;

    for (int c = t; c < 1024; c += 256) {
        const int j = c >> 4, ci = c & 15;
        *(float4*)(Wk_s + j * 68 + ci * 4) = *(const float4*)(Wk + c * 4);
        *(float4*)(Wq_s + j * 68 + ci * 4) = *(const float4*)(Wq + c * 4);
    }
    {
        const int l = t >> 4, ci = t & 15;
        *(float4*)(hs2 + l * 68 + ci * 4) = *(const float4*)(h_tail + (size_t)n * 1024 + t * 4);
    }
    __syncthreads();

    const int l = t >> 4, qd = t & 15;
    float acc[4] = {0.f, 0.f, 0.f, 0.f};
#pragma unroll
    for (int ci = 0; ci < 16; ++ci) {
        const float4 hv = *(const float4*)(hs2 + l * 68 + ci * 4);
#pragma unroll
        for (int c = 0; c < 4; ++c) {
            const int j = qd + 16 * c;
            const float4 wv = *(const float4*)(Wk_s + j * 68 + ci * 4);
            acc[c] += hv.x * wv.x + hv.y * wv.y + hv.z * wv.z + hv.w * wv.w;
        }
    }
    const size_t row = (size_t)n * LL + l;
#pragma unroll
    for (int c = 0; c < 4; ++c) {
        const int col = qd + 16 * c;
        Kmat[row * 64 + col] = acc[c];
        Kh[row * 64 + col] = f2bf(acc[c]);
    }
    if (t < 64) {
        float a = 0.f;
#pragma unroll
        for (int i = 0; i < 64; ++i) a += hs2[15 * 68 + i] * Wq_s[t * 68 + i];
        Qf[(size_t)n * 64 + t] = a;
        Qh[(size_t)n * 64 + t] = f2bf(a);
    }
}

// ---------------------------------------------------------------------------
// Kernel 3: MFMA scores + threshold filter -> candidate emission (unchanged).
// ---------------------------------------------------------------------------
__global__ __launch_bounds__(512) void score_kernel(
    const unsigned short* __restrict__ Kh,  // (32768,64) bf16
    const unsigned short* __restrict__ Qh,  // (2048,64) bf16
    int* __restrict__ cnt,                  // (2048,)
    int* __restrict__ ids)                  // (2048, CAP)
{
    __shared__ float stat_s[8][16];
    __shared__ float stat_q[8][16];
    __shared__ float th_s[16];

    const int t    = threadIdx.x;
    const int wave = t >> 6;
    const int lane = t & 63;
    const int n    = lane & 15;
    const int quad = lane >> 4;

    const int qbase = (blockIdx.x >> 2) * 16;
    const int split = blockIdx.x & 3;
    const int qg    = qbase + n;

    FragCast bq0, bq1;
    bq0.u = *(const uint4*)(Qh + (size_t)qg * 64 + 0 * 32 + quad * 8);
    bq1.u = *(const uint4*)(Qh + (size_t)qg * 64 + 1 * 32 + quad * 8);

    const int tile0 = split * 512 + wave * 64;

    // Pass A: stats over first 8 tiles
    float ssum = 0.f, ssq = 0.f;
    {
        FragCast a0, a1, na0, na1;
        const unsigned short* r0 = Kh + (size_t)(tile0 * 16 + n) * 64;
        a0.u = *(const uint4*)(r0 + quad * 8);
        a1.u = *(const uint4*)(r0 + 32 + quad * 8);
        for (int i = 0; i < 8; ++i) {
            if (i + 1 < 8) {
                const unsigned short* r = Kh + (size_t)((tile0 + i + 1) * 16 + n) * 64;
                na0.u = *(const uint4*)(r + quad * 8);
                na1.u = *(const uint4*)(r + 32 + quad * 8);
            }
            floatx4 acc = {0.f, 0.f, 0.f, 0.f};
            acc = MFMA16(a0.b, bq0.b, acc);
            acc = MFMA16(a1.b, bq1.b, acc);
#pragma unroll
            for (int j = 0; j < 4; ++j) { ssum += acc[j]; ssq += acc[j] * acc[j]; }
            a0 = na0; a1 = na1;
        }
    }
    ssum += __shfl_xor(ssum, 16, 64); ssq += __shfl_xor(ssq, 16, 64);
    ssum += __shfl_xor(ssum, 32, 64); ssq += __shfl_xor(ssq, 32, 64);
    if (lane < 16) { stat_s[wave][n] = ssum; stat_q[wave][n] = ssq; }
    __syncthreads();
    if (t < 16) {
        float S = 0.f, S2 = 0.f;
#pragma unroll
        for (int w = 0; w < 8; ++w) { S += stat_s[w][t]; S2 += stat_q[w][t]; }
        const float inv = 1.f / 1024.f;
        const float mu = S * inv;
        float var = S2 * inv - mu * mu;
        var = var > 0.f ? var : 0.f;
        th_s[t] = mu + 2.6f * __fsqrt_rn(var);
    }
    __syncthreads();
    const float th = th_s[n];

    // Pass B: full 64 tiles, emit candidates above threshold
    int bufid[16];
    int bcnt = 0;
    {
        FragCast a0, a1, na0, na1;
        const unsigned short* r0 = Kh + (size_t)(tile0 * 16 + n) * 64;
        a0.u = *(const uint4*)(r0 + quad * 8);
        a1.u = *(const uint4*)(r0 + 32 + quad * 8);
        for (int i = 0; i < 64; ++i) {
            if (i + 1 < 64) {
                const unsigned short* r = Kh + (size_t)((tile0 + i + 1) * 16 + n) * 64;
                na0.u = *(const uint4*)(r + quad * 8);
                na1.u = *(const uint4*)(r + 32 + quad * 8);
            }
            floatx4 acc = {0.f, 0.f, 0.f, 0.f};
            acc = MFMA16(a0.b, bq0.b, acc);
            acc = MFMA16(a1.b, bq1.b, acc);
            const int rowb = (tile0 + i) * 16 + quad * 4;
#pragma unroll
            for (int j = 0; j < 4; ++j) {
                const float s = acc[j];
                const int rowid = rowb + j;
                if (s > th && (rowid >> 4) != qg && bcnt < 16) {
#pragma unroll
                    for (int k = 0; k < 16; ++k) if (k == bcnt) bufid[k] = rowid;
                    bcnt++;
                }
            }
            a0 = na0; a1 = na1;
        }
    }
    if (bcnt > 0) {
        const int base = atomicAdd(&cnt[qg], bcnt);
#pragma unroll
        for (int k = 0; k < 16; ++k) {
            if (k < bcnt) {
                const int slot = base + k;
                if (slot < CAP) ids[(size_t)qg * CAP + slot] = bufid[k];
            }
        }
    }
}

// ---------------------------------------------------------------------------
// Kernel 4: exact fp32 rescore + top-10 + softmax + MLP. Now 8 q/block,
// grid 256 (1 block/CU).
// ---------------------------------------------------------------------------
__global__ __launch_bounds__(256) void final_kernel(
    const float* __restrict__ x,      // (N,T,F)
    const float* __restrict__ Qf,     // (2048,64)
    const float* __restrict__ Kmat,   // (32768,64)
    const int* __restrict__ cnt,
    const int* __restrict__ ids,
    const float* __restrict__ W1, const float* __restrict__ b1,
    const float* __restrict__ W2, const float* __restrict__ b2,
    float* __restrict__ out)          // (N,)
{
    __shared__ __attribute__((aligned(16))) float Qs[8 * 64];
    __shared__ float sval[8][CAP];    // 30 KB
    __shared__ int cnt_s[8];

    const int t = threadIdx.x;
    const int qbase = blockIdx.x * 8;

    if (t < 128) *(float4*)(Qs + t * 4) = *(const float4*)(Qf + (size_t)qbase * 64 + t * 4);
    if (t < 8) {
        int c = cnt[qbase + t];
        cnt_s[t] = c < CAP ? c : CAP;
    }
    __syncthreads();

    for (int q = 0; q < 8; ++q) {
        const int mc = cnt_s[q];
        const float* qr = Qs + q * 64;
        for (int c = t; c < mc; c += 256) {
            const int id = ids[(size_t)(qbase + q) * CAP + c];
            const float* kr = Kmat + (size_t)id * 64;
            float a0 = 0.f, a1 = 0.f, a2 = 0.f, a3 = 0.f;
#pragma unroll
            for (int i = 0; i < 64; i += 4) {
                a0 += qr[i] * kr[i];
                a1 += qr[i + 1] * kr[i + 1];
                a2 += qr[i + 2] * kr[i + 2];
                a3 += qr[i + 3] * kr[i + 3];
            }
            sval[q][c] = (a0 + a1) + (a2 + a3);
        }
    }
    __syncthreads();

    if (t < 8) {
        const int q = t, mc = cnt_s[q];
        float v[TOPKK]; int vid[TOPKK];
#pragma unroll
        for (int r = 0; r < TOPKK; ++r) { v[r] = -3e38f; vid[r] = -1; }
        float vmin = -3e38f; int imin = 0;
        for (int c = 0; c < mc; ++c) {
            const float s = sval[q][c];
            if (s > vmin) {
                const int id = ids[(size_t)(qbase + q) * CAP + c];
#pragma unroll
                for (int r = 0; r < TOPKK; ++r) if (r == imin) { v[r] = s; vid[r] = id; }
                vmin = v[0]; imin = 0;
#pragma unroll
                for (int r = 1; r < TOPKK; ++r) if (v[r] < vmin) { vmin = v[r]; imin = r; }
            }
        }
        float mx = v[0];
#pragma unroll
        for (int r = 1; r < TOPKK; ++r) mx = v[r] > mx ? v[r] : mx;
        float w[TOPKK]; float sum = 0.f;
#pragma unroll
        for (int r = 0; r < TOPKK; ++r) { w[r] = __expf(v[r] - mx); sum += w[r]; }
        const float inv = 1.f / sum;
        float feat[FF];
#pragma unroll
        for (int f = 0; f < FF; ++f) feat[f] = 0.f;
        for (int r = 0; r < TOPKK; ++r) {
            const int wi = vid[r];
            const int m = wi >> 4, l = wi & 15;
            const float* xr = x + ((size_t)m * TT + (48 + l)) * FF;
            const float wr = w[r] * inv;
#pragma unroll
            for (int f = 0; f < FF; ++f) feat[f] += wr * xr[f];
        }
        float o = 0.f;
#pragma unroll
        for (int oo = 0; oo < FF; ++oo) {
            float hh = b1[oo];
#pragma unroll
            for (int f = 0; f < FF; ++f) hh += feat[f] * W1[oo * FF + f];
            hh = hh > 0.f ? hh : 0.01f * hh;
            o += hh * W2[oo];
        }
        o += b2[0];
        out[qbase + q] = o;
    }
}

// ---------------------------------------------------------------------------
extern "C" void kernel_launch(void* const* d_in, const int* in_sizes, int n_in,
                              void* d_out, int out_size, void* d_ws, size_t ws_size,
                              hipStream_t stream) {
    const float* x    = (const float*)d_in[0];
    const float* W_ih = (const float*)d_in[1];
    const float* W_hh = (const float*)d_in[2];
    const float* b_ih = (const float*)d_in[3];
    const float* b_hh = (const float*)d_in[4];
    const float* Wq   = (const float*)d_in[5];
    const float* Wk   = (const float*)d_in[6];
    const float* W1   = (const float*)d_in[7];
    const float* b1   = (const float*)d_in[8];
    const float* W2   = (const float*)d_in[9];
    const float* b2   = (const float*)d_in[10];
    float* outp = (float*)d_out;
    (void)ws_size; (void)n_in; (void)in_sizes; (void)out_size;

    float* h_tail        = (float*)d_ws;                                 // 8 MB
    int*   ids           = (int*)d_ws;                                   // overlay (after prep consumes h_tail)
    float* Kmat          = h_tail + (size_t)2048 * 1024;                 // 8 MB
    unsigned short* Kh   = (unsigned short*)(Kmat + (size_t)32768 * 64); // 4 MB
    float* Qf            = (float*)(Kh + (size_t)32768 * 64);            // 0.5 MB
    unsigned short* Qh   = (unsigned short*)(Qf + (size_t)2048 * 64);    // 0.25 MB
    int*   cnt           = (int*)(Qh + (size_t)2048 * 64);               // 8 KB

    hipMemsetAsync(cnt, 0, 2048 * sizeof(int), stream);
    gru_kernel<<<NN / 4, 256, 0, stream>>>(x, W_ih, W_hh, b_ih, b_hh, h_tail);
    prep_kernel<<<NN, 256, 0, stream>>>(h_tail, Wk, Wq, Kmat, Kh, Qf, Qh);
    score_kernel<<<512, 512, 0, stream>>>(Kh, Qh, cnt, ids);
    final_kernel<<<NN / 8, 256, 0, stream>>>(x, Qf, Kmat, cnt, ids, W1, b1, W2, b2, outp);
}

// Round 6
// 273.643 us; speedup vs baseline: 2.8362x; 1.1859x over previous
//
#include <hip/hip_runtime.h>

#define NN 2048
#define TT 64
#define FF 16
#define HH 64
#define LL 16
#define TOPKK 10
#define CAP 960

#define AS 72      // Asp row stride in shorts (144 B: 16B-aligned, 2-way banks)
#define XAS 40     // xa row stride in shorts (80 B: 16B-aligned)
#define XPS 196    // xp row stride in floats

typedef __bf16 bf16x8 __attribute__((ext_vector_type(8)));
typedef float floatx4 __attribute__((ext_vector_type(4)));

union FragCast { uint4 u; bf16x8 b; unsigned short s[8]; };

__device__ __forceinline__ unsigned short f2bf(float f) {
    unsigned u = __float_as_uint(f);
    return (unsigned short)((u + 0x7fff + ((u >> 16) & 1)) >> 16);
}
__device__ __forceinline__ float bf2f(unsigned short h) {
    return __uint_as_float(((unsigned)h) << 16);
}
__device__ __forceinline__ void split3(float v, unsigned short& a, unsigned short& b, unsigned short& c) {
    a = f2bf(v); float r = v - bf2f(a);
    b = f2bf(r); float r2 = r - bf2f(b);
    c = f2bf(r2);
}
__device__ __forceinline__ float fsigmoid(float x) {
    return __builtin_amdgcn_rcpf(1.f + __builtin_amdgcn_exp2f(-1.442695041f * x));
}
__device__ __forceinline__ float ftanh(float x) {
    return 1.f - 2.f * __builtin_amdgcn_rcpf(1.f + __builtin_amdgcn_exp2f(2.885390082f * x));
}
__device__ __forceinline__ void async_copy16(const void* g, void* l) {
    __builtin_amdgcn_global_load_lds(
        (const __attribute__((address_space(1))) unsigned int*)g,
        (__attribute__((address_space(3))) unsigned int*)l, 16, 0, 0);
}
#define MFMA16(A, B, C) __builtin_amdgcn_mfma_f32_16x16x32_bf16((A), (B), (C), 0, 0, 0)
// 3-limb x 3-limb emulated-fp32 product set (upper triangle, 6 MFMAs)
#define LIMB6(ACC, A1, A2, A3, W)            \
    ACC = MFMA16((A1), (W)[0], ACC);         \
    ACC = MFMA16((A1), (W)[1], ACC);         \
    ACC = MFMA16((A2), (W)[0], ACC);         \
    ACC = MFMA16((A1), (W)[2], ACC);         \
    ACC = MFMA16((A2), (W)[1], ACC);         \
    ACC = MFMA16((A3), (W)[0], ACC);

// ---------------------------------------------------------------------------
// Kernel 1: MFMA GRU v3. 512 blocks x 256 threads (4 waves), 4 samples/block.
// - x@W_ih.T hoisted out of the recurrence: computed per 4-step chunk into
//   LDS xp (18 MFMAs per chunk) -> per-step MFMA 54 -> 36.
// - Sample s at A-row 4s -> pointwise spread across quads (1 chain/lane).
// - W_hh (72 VGPR) + W_ih (36 VGPR) register-resident; 2 waves/EU.
// ---------------------------------------------------------------------------
__global__ __launch_bounds__(256, 2) void gru_kernel(
    const float* __restrict__ x,      // (N,T,F)
    const float* __restrict__ W_ih,   // (192,16)
    const float* __restrict__ W_hh,   // (192,64)
    const float* __restrict__ b_ih,   // (192,)
    const float* __restrict__ b_hh,   // (192,)
    float* __restrict__ h_tail)       // (N,16,64)
{
    __shared__ __attribute__((aligned(16))) unsigned short Asp[2][3][16 * AS]; // h limb planes, 13.5 KB
    __shared__ __attribute__((aligned(16))) unsigned short xa[3][16 * XAS];    // x limb planes (chunk), 3.75 KB
    __shared__ __attribute__((aligned(16))) float xp[16 * XPS];                // x@W_ih.T (chunk), 12.25 KB
    __shared__ __attribute__((aligned(16))) float x_lds[4 * TT * FF];          // 16 KB

    const int t    = threadIdx.x;
    const int wv   = t >> 6;
    const int lane = t & 63;
    const int nh   = lane & 15;
    const int quad = lane >> 4;
    const int n0   = blockIdx.x * 4;

    // preload x (16 KB) into LDS
    {
        const char* src = (const char*)(x + (size_t)n0 * TT * FF);
        char* dst = (char*)x_lds;
#pragma unroll
        for (int i = 0; i < 4; ++i)
            async_copy16(src + i * 4096 + t * 16, dst + i * 4096 + t * 16);
    }
    // zero limb planes (h0=0; unused rows/cols stay 0 forever)
    {
        unsigned* p = (unsigned*)&Asp[0][0][0];
        for (int i = t; i < 2 * 3 * 16 * AS / 2; i += 256) p[i] = 0;
        unsigned* q = (unsigned*)&xa[0][0];
        for (int i = t; i < 3 * 16 * XAS / 2; i += 256) q[i] = 0;
    }

    // biases for this lane's gate col jb = 16*wv + nh
    const int jb = wv * 16 + nh;
    const float brz = b_ih[jb] + b_hh[jb];
    const float bz  = b_ih[64 + jb] + b_hh[64 + jb];
    const float bxn = b_ih[128 + jb];
    const float bhn = b_hh[128 + jb];

    // W_hh fragments (3 limbs), wave wv owns gate tiles {wv, 4+wv, 8+wv}
    bf16x8 wf[3][2][3];
#pragma unroll
    for (int nt = 0; nt < 3; ++nt) {
        const int gr = (wv + 4 * nt) * 16 + nh;
#pragma unroll
        for (int kc = 0; kc < 2; ++kc) {
            const float* p = W_hh + gr * 64 + kc * 32 + quad * 8;
            FragCast f1, f2, f3;
#pragma unroll
            for (int i = 0; i < 8; ++i) split3(p[i], f1.s[i], f2.s[i], f3.s[i]);
            wf[nt][kc][0] = f1.b; wf[nt][kc][1] = f2.b; wf[nt][kc][2] = f3.b;
        }
    }
    // W_ih fragments (K=16 in cols 0..15 of a 32-col chunk; quads 2,3 zero)
    bf16x8 wfi[3][3];
#pragma unroll
    for (int nt = 0; nt < 3; ++nt) {
        const int gr = (wv + 4 * nt) * 16 + nh;
        FragCast f1, f2, f3;
#pragma unroll
        for (int i = 0; i < 8; ++i) {
            const float v = (quad < 2) ? W_ih[gr * 16 + quad * 8 + i] : 0.f;
            split3(v, f1.s[i], f2.s[i], f3.s[i]);
        }
        wfi[nt][0] = f1.b; wfi[nt][1] = f2.b; wfi[nt][2] = f3.b;
    }

    __syncthreads();   // x_lds staged, zeros visible

    float hprev = 0.f;   // h[sample=quad][col=jb]

    for (int chunk = 0; chunk < 16; ++chunk) {
        // stage x limbs for this chunk: row = sl*4 + p (sl=step-in-chunk, p=sample)
        {
            const int row = t >> 4, f = t & 15;
            const int p = row & 3, sl = row >> 2;
            const float xv = x_lds[p * (TT * FF) + (chunk * 4 + sl) * FF + f];
            unsigned short a, b, c; split3(xv, a, b, c);
            xa[0][row * XAS + f] = a;
            xa[1][row * XAS + f] = b;
            xa[2][row * XAS + f] = c;
        }
        __syncthreads();
        // xp = x_chunk @ W_ih^T  (18 MFMAs per wave)
        {
            floatx4 xacc0 = {0.f,0.f,0.f,0.f}, xacc1 = {0.f,0.f,0.f,0.f}, xacc2 = {0.f,0.f,0.f,0.f};
            const int aoff = nh * XAS + quad * 8;
            FragCast a1, a2, a3;
            a1.u = *(const uint4*)&xa[0][aoff];
            a2.u = *(const uint4*)&xa[1][aoff];
            a3.u = *(const uint4*)&xa[2][aoff];
            LIMB6(xacc0, a1.b, a2.b, a3.b, wfi[0]);
            LIMB6(xacc1, a1.b, a2.b, a3.b, wfi[1]);
            LIMB6(xacc2, a1.b, a2.b, a3.b, wfi[2]);
#pragma unroll
            for (int r = 0; r < 4; ++r) {
                const int m = quad * 4 + r;
                xp[m * XPS + (wv + 0) * 16 + nh] = xacc0[r];
                xp[m * XPS + (wv + 4) * 16 + nh] = xacc1[r];
                xp[m * XPS + (wv + 8) * 16 + nh] = xacc2[r];
            }
        }
        __syncthreads();

#pragma unroll
        for (int si = 0; si < 4; ++si) {
            const int step = chunk * 4 + si;
            const int rb = step & 1, wb = rb ^ 1;
            floatx4 acc0 = {0.f,0.f,0.f,0.f}, acc1 = {0.f,0.f,0.f,0.f}, acc2 = {0.f,0.f,0.f,0.f};
#pragma unroll
            for (int kc = 0; kc < 2; ++kc) {
                const int aoff = nh * AS + kc * 32 + quad * 8;
                FragCast a1, a2, a3;
                a1.u = *(const uint4*)&Asp[rb][0][aoff];
                a2.u = *(const uint4*)&Asp[rb][1][aoff];
                a3.u = *(const uint4*)&Asp[rb][2][aoff];
                LIMB6(acc0, a1.b, a2.b, a3.b, wf[0][kc]);
                LIMB6(acc1, a1.b, a2.b, a3.b, wf[1][kc]);
                LIMB6(acc2, a1.b, a2.b, a3.b, wf[2][kc]);
            }
            // pointwise: lane (quad=sample p, nh) uses reg 0 (row 4p), col jb
            {
                const int xrow = si * 4 + quad;
                const float xr = xp[xrow * XPS + jb];
                const float xz = xp[xrow * XPS + 64 + jb];
                const float xn = xp[xrow * XPS + 128 + jb];
                const float rg = fsigmoid(acc0[0] + xr + brz);
                const float zg = fsigmoid(acc1[0] + xz + bz);
                const float ng = ftanh((xn + bxn) + rg * (acc2[0] + bhn));
                const float h  = (1.f - zg) * ng + zg * hprev;
                hprev = h;
                unsigned short la, lb2, lc; split3(h, la, lb2, lc);
                const int ho = (4 * quad) * AS + jb;
                Asp[wb][0][ho] = la;
                Asp[wb][1][ho] = lb2;
                Asp[wb][2][ho] = lc;
                if (step >= TT - LL)
                    h_tail[((size_t)(n0 + quad) * LL + (step - (TT - LL))) * HH + jb] = h;
            }
            __syncthreads();
        }
    }
}

// ---------------------------------------------------------------------------
// Kernel 2: prep (unchanged). K rows + Q rows, fp32 + bf16.
// ---------------------------------------------------------------------------
__global__ __launch_bounds__(256) void prep_kernel(
    const float* __restrict__ h_tail, // (N,16,64)
    const float* __restrict__ Wk,     // (64,64)
    const float* __restrict__ Wq,     // (64,64)
    float* __restrict__ Kmat,         // (32768,64) fp32
    unsigned short* __restrict__ Kh,  // (32768,64) bf16
    float* __restrict__ Qf,           // (2048,64) fp32
    unsigned short* __restrict__ Qh)  // (2048,64) bf16
{
    __shared__ __attribute__((aligned(16))) float Wk_s[64 * 68];
    __shared__ __attribute__((aligned(16))) float Wq_s[64 * 68];
    __shared__ __attribute__((aligned(16))) float hs2[16 * 68];
    const int t = threadIdx.x;
    const int n = blockIdx.x;

    for (int c = t; c < 1024; c += 256) {
        const int j = c >> 4, ci = c & 15;
        *(float4*)(Wk_s + j * 68 + ci * 4) = *(const float4*)(Wk + c * 4);
        *(float4*)(Wq_s + j * 68 + ci * 4) = *(const float4*)(Wq + c * 4);
    }
    {
        const int l = t >> 4, ci = t & 15;
        *(float4*)(hs2 + l * 68 + ci * 4) = *(const float4*)(h_tail + (size_t)n * 1024 + t * 4);
    }
    __syncthreads();

    const int l = t >> 4, qd = t & 15;
    float acc[4] = {0.f, 0.f, 0.f, 0.f};
#pragma unroll
    for (int ci = 0; ci < 16; ++ci) {
        const float4 hv = *(const float4*)(hs2 + l * 68 + ci * 4);
#pragma unroll
        for (int c = 0; c < 4; ++c) {
            const int j = qd + 16 * c;
            const float4 wv = *(const float4*)(Wk_s + j * 68 + ci * 4);
            acc[c] += hv.x * wv.x + hv.y * wv.y + hv.z * wv.z + hv.w * wv.w;
        }
    }
    const size_t row = (size_t)n * LL + l;
#pragma unroll
    for (int c = 0; c < 4; ++c) {
        const int col = qd + 16 * c;
        Kmat[row * 64 + col] = acc[c];
        Kh[row * 64 + col] = f2bf(acc[c]);
    }
    if (t < 64) {
        float a = 0.f;
#pragma unroll
        for (int i = 0; i < 64; ++i) a += hs2[15 * 68 + i] * Wq_s[t * 68 + i];
        Qf[(size_t)n * 64 + t] = a;
        Qh[(size_t)n * 64 + t] = f2bf(a);
    }
}

// ---------------------------------------------------------------------------
// Kernel 3: MFMA scores + threshold filter, Qtile=64.
// Grid: 32 qgroups x 16 splits = 512 blocks x 512 threads (8 waves).
// Each wave: 16 K-tiles x 4 query-subtiles (8 MFMAs per K-tile load).
// ---------------------------------------------------------------------------
__global__ __launch_bounds__(512, 4) void score_kernel(
    const unsigned short* __restrict__ Kh,  // (32768,64) bf16
    const unsigned short* __restrict__ Qh,  // (2048,64) bf16
    int* __restrict__ cnt,                  // (2048,)
    int* __restrict__ ids)                  // (2048, CAP)
{
    __shared__ float stat_s[8][4][16];
    __shared__ float stat_q[8][4][16];
    __shared__ float th_s[64];

    const int t    = threadIdx.x;
    const int wave = t >> 6;
    const int lane = t & 63;
    const int n    = lane & 15;
    const int quad = lane >> 4;

    const int qgroup = blockIdx.x >> 4;   // 0..31
    const int split  = blockIdx.x & 15;   // 0..15
    const int tile0  = split * 128 + wave * 16;

    // B fragments: 4 query-subtiles
    FragCast bq[4][2];
#pragma unroll
    for (int qs = 0; qs < 4; ++qs) {
        const int qg = qgroup * 64 + qs * 16 + n;
        bq[qs][0].u = *(const uint4*)(Qh + (size_t)qg * 64 + quad * 8);
        bq[qs][1].u = *(const uint4*)(Qh + (size_t)qg * 64 + 32 + quad * 8);
    }

    // ---- Pass A: stats over this wave's first 8 tiles (block total: 1024 rows) ----
    float ssum[4] = {0.f,0.f,0.f,0.f}, ssq[4] = {0.f,0.f,0.f,0.f};
    for (int i = 0; i < 8; ++i) {
        const unsigned short* r = Kh + (size_t)((tile0 + i) * 16 + n) * 64;
        FragCast a0, a1;
        a0.u = *(const uint4*)(r + quad * 8);
        a1.u = *(const uint4*)(r + 32 + quad * 8);
#pragma unroll
        for (int qs = 0; qs < 4; ++qs) {
            floatx4 acc = {0.f, 0.f, 0.f, 0.f};
            acc = MFMA16(a0.b, bq[qs][0].b, acc);
            acc = MFMA16(a1.b, bq[qs][1].b, acc);
#pragma unroll
            for (int j = 0; j < 4; ++j) { ssum[qs] += acc[j]; ssq[qs] += acc[j] * acc[j]; }
        }
    }
#pragma unroll
    for (int qs = 0; qs < 4; ++qs) {
        ssum[qs] += __shfl_xor(ssum[qs], 16, 64); ssq[qs] += __shfl_xor(ssq[qs], 16, 64);
        ssum[qs] += __shfl_xor(ssum[qs], 32, 64); ssq[qs] += __shfl_xor(ssq[qs], 32, 64);
    }
    if (lane < 16) {
#pragma unroll
        for (int qs = 0; qs < 4; ++qs) { stat_s[wave][qs][n] = ssum[qs]; stat_q[wave][qs][n] = ssq[qs]; }
    }
    __syncthreads();
    if (t < 64) {
        const int qs = t >> 4, c = t & 15;
        float S = 0.f, S2 = 0.f;
#pragma unroll
        for (int w = 0; w < 8; ++w) { S += stat_s[w][qs][c]; S2 += stat_q[w][qs][c]; }
        const float inv = 1.f / 1024.f;
        const float mu = S * inv;
        float var = S2 * inv - mu * mu;
        var = var > 0.f ? var : 0.f;
        th_s[t] = mu + 2.6f * __fsqrt_rn(var);
    }
    __syncthreads();
    float th[4];
#pragma unroll
    for (int qs = 0; qs < 4; ++qs) th[qs] = th_s[qs * 16 + n];

    // ---- Pass B: 16 tiles, emit (query,row) above threshold ----
    int bufp[16];
    int bcnt = 0;
    {
        FragCast a0, a1, na0, na1;
        const unsigned short* r0 = Kh + (size_t)(tile0 * 16 + n) * 64;
        a0.u = *(const uint4*)(r0 + quad * 8);
        a1.u = *(const uint4*)(r0 + 32 + quad * 8);
        for (int i = 0; i < 16; ++i) {
            if (i + 1 < 16) {
                const unsigned short* r = Kh + (size_t)((tile0 + i + 1) * 16 + n) * 64;
                na0.u = *(const uint4*)(r + quad * 8);
                na1.u = *(const uint4*)(r + 32 + quad * 8);
            }
            const int rowb = (tile0 + i) * 16 + quad * 4;
#pragma unroll
            for (int qs = 0; qs < 4; ++qs) {
                floatx4 acc = {0.f, 0.f, 0.f, 0.f};
                acc = MFMA16(a0.b, bq[qs][0].b, acc);
                acc = MFMA16(a1.b, bq[qs][1].b, acc);
                const int qg = qgroup * 64 + qs * 16 + n;
#pragma unroll
                for (int j = 0; j < 4; ++j) {
                    const float s = acc[j];
                    const int rowid = rowb + j;
                    if (s > th[qs] && (rowid >> 4) != qg && bcnt < 16) {
                        const int pk = qg * 32768 + rowid;
#pragma unroll
                        for (int k = 0; k < 16; ++k) if (k == bcnt) bufp[k] = pk;
                        bcnt++;
                    }
                }
            }
            a0 = na0; a1 = na1;
        }
    }
    if (bcnt > 0) {
#pragma unroll
        for (int k = 0; k < 16; ++k) {
            if (k < bcnt) {
                const int pk = bufp[k];
                const int qid = pk >> 15, rid = pk & 32767;
                const int slot = atomicAdd(&cnt[qid], 1);
                if (slot < CAP) ids[(size_t)qid * CAP + slot] = rid;
            }
        }
    }
}

// ---------------------------------------------------------------------------
// Kernel 4: exact fp32 rescore + top-10 + softmax + MLP (unchanged).
// ---------------------------------------------------------------------------
__global__ __launch_bounds__(256) void final_kernel(
    const float* __restrict__ x,      // (N,T,F)
    const float* __restrict__ Qf,     // (2048,64)
    const float* __restrict__ Kmat,   // (32768,64)
    const int* __restrict__ cnt,
    const int* __restrict__ ids,
    const float* __restrict__ W1, const float* __restrict__ b1,
    const float* __restrict__ W2, const float* __restrict__ b2,
    float* __restrict__ out)          // (N,)
{
    __shared__ __attribute__((aligned(16))) float Qs[8 * 64];
    __shared__ float sval[8][CAP];    // 30 KB
    __shared__ int cnt_s[8];

    const int t = threadIdx.x;
    const int qbase = blockIdx.x * 8;

    if (t < 128) *(float4*)(Qs + t * 4) = *(const float4*)(Qf + (size_t)qbase * 64 + t * 4);
    if (t < 8) {
        int c = cnt[qbase + t];
        cnt_s[t] = c < CAP ? c : CAP;
    }
    __syncthreads();

    for (int q = 0; q < 8; ++q) {
        const int mc = cnt_s[q];
        const float* qr = Qs + q * 64;
        for (int c = t; c < mc; c += 256) {
            const int id = ids[(size_t)(qbase + q) * CAP + c];
            const float* kr = Kmat + (size_t)id * 64;
            float a0 = 0.f, a1 = 0.f, a2 = 0.f, a3 = 0.f;
#pragma unroll
            for (int i = 0; i < 64; i += 4) {
                a0 += qr[i] * kr[i];
                a1 += qr[i + 1] * kr[i + 1];
                a2 += qr[i + 2] * kr[i + 2];
                a3 += qr[i + 3] * kr[i + 3];
            }
            sval[q][c] = (a0 + a1) + (a2 + a3);
        }
    }
    __syncthreads();

    if (t < 8) {
        const int q = t, mc = cnt_s[q];
        float v[TOPKK]; int vid[TOPKK];
#pragma unroll
        for (int r = 0; r < TOPKK; ++r) { v[r] = -3e38f; vid[r] = -1; }
        float vmin = -3e38f; int imin = 0;
        for (int c = 0; c < mc; ++c) {
            const float s = sval[q][c];
            if (s > vmin) {
                const int id = ids[(size_t)(qbase + q) * CAP + c];
#pragma unroll
                for (int r = 0; r < TOPKK; ++r) if (r == imin) { v[r] = s; vid[r] = id; }
                vmin = v[0]; imin = 0;
#pragma unroll
                for (int r = 1; r < TOPKK; ++r) if (v[r] < vmin) { vmin = v[r]; imin = r; }
            }
        }
        float mx = v[0];
#pragma unroll
        for (int r = 1; r < TOPKK; ++r) mx = v[r] > mx ? v[r] : mx;
        float w[TOPKK]; float sum = 0.f;
#pragma unroll
        for (int r = 0; r < TOPKK; ++r) { w[r] = __expf(v[r] - mx); sum += w[r]; }
        const float inv = 1.f / sum;
        float feat[FF];
#pragma unroll
        for (int f = 0; f < FF; ++f) feat[f] = 0.f;
        for (int r = 0; r < TOPKK; ++r) {
            const int wi = vid[r];
            const int m = wi >> 4, l = wi & 15;
            const float* xr = x + ((size_t)m * TT + (48 + l)) * FF;
            const float wr = w[r] * inv;
#pragma unroll
            for (int f = 0; f < FF; ++f) feat[f] += wr * xr[f];
        }
        float o = 0.f;
#pragma unroll
        for (int oo = 0; oo < FF; ++oo) {
            float hh = b1[oo];
#pragma unroll
            for (int f = 0; f < FF; ++f) hh += feat[f] * W1[oo * FF + f];
            hh = hh > 0.f ? hh : 0.01f * hh;
            o += hh * W2[oo];
        }
        o += b2[0];
        out[qbase + t] = o;
    }
}

// ---------------------------------------------------------------------------
extern "C" void kernel_launch(void* const* d_in, const int* in_sizes, int n_in,
                              void* d_out, int out_size, void* d_ws, size_t ws_size,
                              hipStream_t stream) {
    const float* x    = (const float*)d_in[0];
    const float* W_ih = (const float*)d_in[1];
    const float* W_hh = (const float*)d_in[2];
    const float* b_ih = (const float*)d_in[3];
    const float* b_hh = (const float*)d_in[4];
    const float* Wq   = (const float*)d_in[5];
    const float* Wk   = (const float*)d_in[6];
    const float* W1   = (const float*)d_in[7];
    const float* b1   = (const float*)d_in[8];
    const float* W2   = (const float*)d_in[9];
    const float* b2   = (const float*)d_in[10];
    float* outp = (float*)d_out;
    (void)ws_size; (void)n_in; (void)in_sizes; (void)out_size;

    float* h_tail        = (float*)d_ws;                                 // 8 MB
    int*   ids           = (int*)d_ws;                                   // overlay (after prep consumes h_tail)
    float* Kmat          = h_tail + (size_t)2048 * 1024;                 // 8 MB
    unsigned short* Kh   = (unsigned short*)(Kmat + (size_t)32768 * 64); // 4 MB
    float* Qf            = (float*)(Kh + (size_t)32768 * 64);            // 0.5 MB
    unsigned short* Qh   = (unsigned short*)(Qf + (size_t)2048 * 64);    // 0.25 MB
    int*   cnt           = (int*)(Qh + (size_t)2048 * 64);               // 8 KB

    hipMemsetAsync(cnt, 0, 2048 * sizeof(int), stream);
    gru_kernel<<<NN / 4, 256, 0, stream>>>(x, W_ih, W_hh, b_ih, b_hh, h_tail);
    prep_kernel<<<NN, 256, 0, stream>>>(h_tail, Wk, Wq, Kmat, Kh, Qf, Qh);
    score_kernel<<<512, 512, 0, stream>>>(Kh, Qh, cnt, ids);
    final_kernel<<<NN / 8, 256, 0, stream>>>(x, Qf, Kmat, cnt, ids, W1, b1, W2, b2, outp);
}